// Round 8
// baseline (187.860 us; speedup 1.0000x reference)
//
#include <hip/hip_runtime.h>
#include <math.h>

#define BB 4
#define TT 2048
#define TTP 2112   // TT + 64 zero pad rows per head (pe)
#define NEMB 256
#define NH 8
#define HD 32

typedef __attribute__((ext_vector_type(8))) short bf8;   // 8 x bf16 (4 VGPRs)
typedef __attribute__((ext_vector_type(4))) float f4;    // MFMA C/D

static __device__ __forceinline__ unsigned short f2bf(float f) {
    union { float f; unsigned u; } v; v.f = f;
    unsigned r = v.u + 0x7FFF + ((v.u >> 16) & 1);       // RNE
    return (unsigned short)(r >> 16);
}
static __device__ __forceinline__ float bf2f(unsigned short s) {
    union { unsigned u; float f; } v; v.u = ((unsigned)s) << 16;
    return v.f;
}

// DPP cross-lane move within 16-lane rows (VALU pipe)
template <int CTRL>
static __device__ __forceinline__ float dppmv(float x) {
    return __int_as_float(__builtin_amdgcn_mov_dpp(__float_as_int(x), CTRL, 0xF, 0xF, true));
}
static __device__ __forceinline__ float rowsum16(float x) {
    x += dppmv<0xB1>(x);
    x += dppmv<0x4E>(x);
    x += dppmv<0x124>(x);
    x += dppmv<0x128>(x);
    return x;
}

// ---------------- fused prep: pe->bf16 (+zero pad), w_attn^T, w_proj^T -------
static __device__ __forceinline__ void tcvt_body(const float* __restrict__ src,
                                                 unsigned short* __restrict__ dst,
                                                 int R, int C, int gx, int gy,
                                                 float (*t)[65], int tid) {
    const int c0 = gx * 64, r0 = gy * 64;
    #pragma unroll
    for (int p = 0; p < 4; ++p) {
        const int i = tid + p * 256;
        const int r = i >> 4, c4 = (i & 15) * 4;
        const float4 v = *(const float4*)(src + (long)(r0 + r) * C + c0 + c4);
        t[r][c4] = v.x; t[r][c4+1] = v.y; t[r][c4+2] = v.z; t[r][c4+3] = v.w;
    }
    __syncthreads();
    #pragma unroll
    for (int p = 0; p < 4; ++p) {
        const int i = tid + p * 256;
        const int cr = i >> 4, r4 = (i & 15) * 4;
        ushort4 vv;
        vv.x = f2bf(t[r4+0][cr]); vv.y = f2bf(t[r4+1][cr]);
        vv.z = f2bf(t[r4+2][cr]); vv.w = f2bf(t[r4+3][cr]);
        *(ushort4*)(dst + (long)(c0 + cr) * R + r0 + r4) = vv;
    }
}

__global__ __launch_bounds__(256) void prep(const float* __restrict__ pe,
                                            unsigned short* __restrict__ peb,
                                            const float* __restrict__ wa,
                                            unsigned short* __restrict__ waT,
                                            const float* __restrict__ wp,
                                            unsigned short* __restrict__ wpT) {
    __shared__ float t[64][65];
    const int bx = blockIdx.x, tid = threadIdx.x;
    if (bx < 528) {                              // pe -> [8][2112][32] bf16, pad=0
        const int idx4 = bx * 256 + tid;
        const int h   = idx4 / 16896;
        const int rem = idx4 - h * 16896;
        const int u   = rem >> 3;
        const int d4  = (rem & 7) * 4;
        ushort4 o = make_ushort4(0, 0, 0, 0);
        if (u < TT) {
            const float4 v = *(const float4*)(pe + ((long)(h * TT + u)) * HD + d4);
            o.x = f2bf(v.x); o.y = f2bf(v.y); o.z = f2bf(v.z); o.w = f2bf(v.w);
        }
        *(ushort4*)(peb + ((long)(h * TTP + u)) * HD + d4) = o;
    } else if (bx < 576) {
        const int lo = bx - 528;                 // w_attn [256][768] -> [768][256]
        tcvt_body(wa, waT, 256, 768, lo % 12, lo / 12, t, tid);
    } else {
        const int lo = bx - 576;                 // w_proj transpose
        tcvt_body(wp, wpT, 256, 256, lo % 4, lo / 4, t, tid);
    }
}

// ---------------- Kernel A: MFMA qkv GEMM, fp32 A inline-converted -----------
// Q pre-scaled by (1/sqrt(32)) * log2(e) so attention uses raw exp2.
__global__ __launch_bounds__(256) void qkv_mfma(const float* __restrict__ xg,
                                                const unsigned short* __restrict__ Bg,
                                                unsigned short* __restrict__ Kb,
                                                unsigned short* __restrict__ Qb,
                                                unsigned short* __restrict__ Vt) {
    __shared__ unsigned short sm[13824];             // 27648 B
    unsigned short* As = sm;                         // [128][72]
    unsigned short* Bs = sm + 9216;                  // [64][72]
    const int tid = threadIdx.x;
    const int wv = tid >> 6, L = tid & 63;
    const int l15 = L & 15, q = L >> 4;
    const int n0 = blockIdx.x * 64;
    const int m0 = blockIdx.y * 128;

    f4 acc[2][4];
    #pragma unroll
    for (int mt = 0; mt < 2; ++mt)
        #pragma unroll
        for (int nt = 0; nt < 4; ++nt) acc[mt][nt] = (f4){0.f,0.f,0.f,0.f};

    for (int kc = 0; kc < 4; ++kc) {
        const int k0 = kc * 64;
        __syncthreads();
        #pragma unroll
        for (int p = 0; p < 4; ++p) {
            const int i = tid + p * 256;
            const int r = i >> 3, c = i & 7;
            const float4 va = *(const float4*)(xg + (long)(m0 + r) * 256 + k0 + c * 8);
            const float4 vb = *(const float4*)(xg + (long)(m0 + r) * 256 + k0 + c * 8 + 4);
            ushort4 lo, hi;
            lo.x = f2bf(va.x); lo.y = f2bf(va.y); lo.z = f2bf(va.z); lo.w = f2bf(va.w);
            hi.x = f2bf(vb.x); hi.y = f2bf(vb.y); hi.z = f2bf(vb.z); hi.w = f2bf(vb.w);
            *(ushort4*)(As + r * 72 + c * 8)     = lo;
            *(ushort4*)(As + r * 72 + c * 8 + 4) = hi;
        }
        #pragma unroll
        for (int p = 0; p < 2; ++p) {
            const int i = tid + p * 256;
            const int r = i >> 3, c = i & 7;
            *(bf8*)(Bs + r * 72 + c * 8) = *(const bf8*)(Bg + (long)(n0 + r) * 256 + k0 + c * 8);
        }
        __syncthreads();
        #pragma unroll
        for (int kk = 0; kk < 2; ++kk) {
            const bf8 a0 = *(const bf8*)(As + (wv * 32 + l15) * 72 + kk * 32 + q * 8);
            const bf8 a1 = *(const bf8*)(As + (wv * 32 + 16 + l15) * 72 + kk * 32 + q * 8);
            #pragma unroll
            for (int nt = 0; nt < 4; ++nt) {
                const bf8 bb = *(const bf8*)(Bs + (nt * 16 + l15) * 72 + kk * 32 + q * 8);
                acc[0][nt] = __builtin_amdgcn_mfma_f32_16x16x32_bf16(a0, bb, acc[0][nt], 0, 0, 0);
                acc[1][nt] = __builtin_amdgcn_mfma_f32_16x16x32_bf16(a1, bb, acc[1][nt], 0, 0, 0);
            }
        }
    }

    const int sec = n0 >> 8;                         // 0=K,1=Q,2=V
    #pragma unroll
    for (int mt = 0; mt < 2; ++mt) {
        const int gm = m0 + wv * 32 + mt * 16 + q * 4;
        const int b = gm >> 11, tb = gm & 2047;
        #pragma unroll
        for (int nt = 0; nt < 4; ++nt) {
            const int gn = n0 + nt * 16 + l15;
            const int cc = gn & 255, h = cc >> 5, d = cc & 31;
            const long bh = (long)b * NH + h;
            const f4 a = acc[mt][nt];
            if (sec == 2) {
                ushort4 vv;
                vv.x = f2bf(a[0]); vv.y = f2bf(a[1]); vv.z = f2bf(a[2]); vv.w = f2bf(a[3]);
                *(ushort4*)(Vt + (bh * HD + d) * TT + tb) = vv;
            } else if (sec == 1) {
                #pragma unroll
                for (int r = 0; r < 4; ++r)
                    Qb[(bh * TT + tb + r) * HD + d] = f2bf(a[r] * 0.25506655788696527f);
            } else {
                #pragma unroll
                for (int r = 0; r < 4; ++r)
                    Kb[(bh * TT + tb + r) * HD + d] = f2bf(a[r]);
            }
        }
    }
}

// ---------------- Kernel B: flash attention, direct-L2 frags, no barriers ----
// K/pe/V MFMA fragments loaded straight from global (L2-resident); LDS holds
// only the per-wave P round-trip. Static-max softmax (acc init -16), raw
// partial O + l per s-split block; merge happens in proj's A-staging.
__global__ __launch_bounds__(256) void attn_kernel(const unsigned short* __restrict__ Kb,
                                                   const unsigned short* __restrict__ Qb,
                                                   const unsigned short* __restrict__ Vtg,
                                                   const unsigned short* __restrict__ peb,
                                                   unsigned short* __restrict__ po,
                                                   float* __restrict__ pl) {
    __shared__ unsigned short Pall[4608];            // 4 waves x [16][72]
    unsigned short* Psw = Pall + (threadIdx.x >> 6) * 1152;

    const int tid = threadIdx.x;
    const int wv  = tid >> 6;
    const int L   = tid & 63;
    const int l15 = L & 15;
    const int q   = L >> 4;
    const int pair = blockIdx.x >> 1;
    const int sblk = blockIdx.x & 1;
    const int h = blockIdx.y, b = blockIdx.z;
    const long bh = (long)b * NH + h;
    const unsigned short* Kg = Kb  + bh * TT * HD;
    const unsigned short* Qg = Qb  + bh * TT * HD;
    const unsigned short* Vg = Vtg + bh * HD * TT;
    const unsigned short* Pg = peb + (long)h * TTP * HD;

    const f4 z4 = {0.f, 0.f, 0.f, 0.f};
    const f4 m4 = {-16.f, -16.f, -16.f, -16.f};      // static softmax max

    // hoisted skew-gather controls (per r): source lane + perm half-select
    int saddr[4]; unsigned psel[4];
    #pragma unroll
    for (int r = 0; r < 4; ++r) {
        const int tcol = l15 + 15 - 4 * q - r;       // 0..30
        saddr[r] = ((q << 4) | (tcol & 15)) << 2;
        psel[r]  = (tcol < 16) ? 0x01000C0Cu : 0x03020C0Cu;
    }
    const int pebase = 48 - 16 * wv;

    for (int half = 0; half < 2; ++half) {
        const int itile = half ? 31 - pair : pair;
        const int t0 = itile * 64;

        const bf8 aq = *(const bf8*)(Qg + (t0 + wv * 16 + l15) * HD + q * 8);
        f4 o0 = z4, o1 = z4;
        float l_st[4] = {0.f, 0.f, 0.f, 0.f};

        for (int jt = sblk; jt <= itile; jt += 2) {
            const int s0 = jt * 64;
            const int ub = TT - 64 - t0 + s0 + pebase;   // wave's pe band base

            // ---- direct global (L2) fragment loads ----
            bf8 bk[4], bp[5], bva[2], bvb[2];
            #pragma unroll
            for (int nt = 0; nt < 4; ++nt)
                bk[nt] = *(const bf8*)(Kg + (long)(s0 + nt * 16 + l15) * HD + q * 8);
            #pragma unroll
            for (int nt = 0; nt < 5; ++nt)
                bp[nt] = *(const bf8*)(Pg + (long)(ub + nt * 16 + l15) * HD + q * 8);
            #pragma unroll
            for (int ks = 0; ks < 2; ++ks) {
                bva[ks] = *(const bf8*)(Vg + (long)l15 * TT + s0 + ks * 32 + q * 8);
                bvb[ks] = *(const bf8*)(Vg + (long)(16 + l15) * TT + s0 + ks * 32 + q * 8);
            }

            f4 sa[4], ra[5];
            #pragma unroll
            for (int nt = 0; nt < 4; ++nt)
                sa[nt] = __builtin_amdgcn_mfma_f32_16x16x32_bf16(aq, bk[nt], m4, 0, 0, 0);
            #pragma unroll
            for (int nt = 0; nt < 5; ++nt)
                ra[nt] = __builtin_amdgcn_mfma_f32_16x16x32_bf16(aq, bp[nt], z4, 0, 0, 0);

            // ---- skew gather: v_perm pack + bpermute + v_perm select ----
            #pragma unroll
            for (int nb = 0; nb < 4; ++nb) {
                #pragma unroll
                for (int r = 0; r < 4; ++r) {
                    const unsigned packed = __builtin_amdgcn_perm(
                        (unsigned)__float_as_int(ra[nb + 1][r]),
                        (unsigned)__float_as_int(ra[nb][r]), 0x07060302u);
                    const int v = __builtin_amdgcn_ds_bpermute(saddr[r], (int)packed);
                    const unsigned sel = __builtin_amdgcn_perm((unsigned)v, (unsigned)v, psel[r]);
                    sa[nb][r] += __int_as_float((int)sel);
                }
            }

            if (jt == itile) {                       // causal mask (diagonal tile)
                #pragma unroll
                for (int nb = 0; nb < 4; ++nb)
                    #pragma unroll
                    for (int r = 0; r < 4; ++r) {
                        const int s_l = nb * 16 + l15;
                        const int t_l = wv * 16 + 4 * q + r;
                        if (s_l > t_l) sa[nb][r] = -1e30f;
                    }
            }

            // ---- static-max softmax: p = exp2(sa); accumulate l per lane ----
            #pragma unroll
            for (int r = 0; r < 4; ++r) {
                #pragma unroll
                for (int nb = 0; nb < 4; ++nb) {
                    const float p = exp2f(sa[nb][r]);
                    l_st[r] += p;
                    const unsigned pu = (unsigned)__float_as_int(p);
                    Psw[(4 * q + r) * 72 + nb * 16 + l15] =
                        (unsigned short)((pu + 0x8000u) >> 16);
                }
            }

            // ---- PV: O += P @ V ----
            #pragma unroll
            for (int ks = 0; ks < 2; ++ks) {
                const bf8 ap = *(const bf8*)(Psw + l15 * 72 + ks * 32 + q * 8);
                o0 = __builtin_amdgcn_mfma_f32_16x16x32_bf16(ap, bva[ks], o0, 0, 0, 0);
                o1 = __builtin_amdgcn_mfma_f32_16x16x32_bf16(ap, bvb[ks], o1, 0, 0, 0);
            }
        }

        // ---- epilogue: raw partial O (bf16) + row l ----
        const long pt = (bh * 32 + itile) * 2 + sblk;
        unsigned short* pob = po + pt * 2048;
        #pragma unroll
        for (int r = 0; r < 4; ++r) {
            const int row = wv * 16 + 4 * q + r;
            pob[row * 32 + l15]      = f2bf(o0[r]);
            pob[row * 32 + 16 + l15] = f2bf(o1[r]);
            const float ls = rowsum16(l_st[r]);
            if (l15 == 0) pl[pt * 64 + row] = ls;
        }
    }
}

// ---------------- Kernel C: proj GEMM + fused s-split merge + bias -----------
// A-staging reads both raw partials + l0/l1 and merges inline: no attb array.
__global__ __launch_bounds__(256) void proj_mfma(const unsigned short* __restrict__ po,
                                                 const float* __restrict__ pl,
                                                 const unsigned short* __restrict__ Bg,
                                                 const float* __restrict__ bias,
                                                 float* __restrict__ out) {
    __shared__ unsigned short sm[13824];
    unsigned short* As = sm;                         // [128][72]
    unsigned short* Bs = sm + 9216;                  // [64][72]
    const int tid = threadIdx.x;
    const int wv = tid >> 6, L = tid & 63;
    const int l15 = L & 15, q = L >> 4;
    const int n0 = blockIdx.x * 64;
    const int m0 = blockIdx.y * 128;

    f4 acc[2][4];
    #pragma unroll
    for (int mt = 0; mt < 2; ++mt)
        #pragma unroll
        for (int nt = 0; nt < 4; ++nt) acc[mt][nt] = (f4){0.f,0.f,0.f,0.f};

    for (int kc = 0; kc < 4; ++kc) {
        const int k0 = kc * 64;
        __syncthreads();
        #pragma unroll
        for (int p = 0; p < 4; ++p) {
            const int i = tid + p * 256;
            const int r = i >> 3, c = i & 7;
            const int gm = m0 + r;
            const int bloc = gm >> 11, t = gm & 2047;
            const int k = k0 + c * 8;
            const int hh = k >> 5, d0 = k & 31;
            const int tile = t >> 6, row = t & 63;
            const long pt0 = ((long)(bloc * NH + hh) * 32 + tile) * 2;
            const float l0 = pl[pt0 * 64 + row];
            const float l1 = pl[pt0 * 64 + 64 + row];
            const float inv = 1.0f / (l0 + l1);
            const unsigned short* p0 = po + pt0 * 2048 + row * 32 + d0;
            const unsigned short* p1 = p0 + 2048;
            const ushort4 a0 = *(const ushort4*)p0;
            const ushort4 a1 = *(const ushort4*)(p0 + 4);
            const ushort4 c0 = *(const ushort4*)p1;
            const ushort4 c1 = *(const ushort4*)(p1 + 4);
            ushort4 o0, o1;
            o0.x = f2bf((bf2f(a0.x) + bf2f(c0.x)) * inv);
            o0.y = f2bf((bf2f(a0.y) + bf2f(c0.y)) * inv);
            o0.z = f2bf((bf2f(a0.z) + bf2f(c0.z)) * inv);
            o0.w = f2bf((bf2f(a0.w) + bf2f(c0.w)) * inv);
            o1.x = f2bf((bf2f(a1.x) + bf2f(c1.x)) * inv);
            o1.y = f2bf((bf2f(a1.y) + bf2f(c1.y)) * inv);
            o1.z = f2bf((bf2f(a1.z) + bf2f(c1.z)) * inv);
            o1.w = f2bf((bf2f(a1.w) + bf2f(c1.w)) * inv);
            *(ushort4*)(As + r * 72 + c * 8)     = o0;
            *(ushort4*)(As + r * 72 + c * 8 + 4) = o1;
        }
        #pragma unroll
        for (int p = 0; p < 2; ++p) {
            const int i = tid + p * 256;
            const int r = i >> 3, c = i & 7;
            *(bf8*)(Bs + r * 72 + c * 8) = *(const bf8*)(Bg + (long)(n0 + r) * 256 + k0 + c * 8);
        }
        __syncthreads();
        #pragma unroll
        for (int kk = 0; kk < 2; ++kk) {
            const bf8 a0 = *(const bf8*)(As + (wv * 32 + l15) * 72 + kk * 32 + q * 8);
            const bf8 a1 = *(const bf8*)(As + (wv * 32 + 16 + l15) * 72 + kk * 32 + q * 8);
            #pragma unroll
            for (int nt = 0; nt < 4; ++nt) {
                const bf8 bb = *(const bf8*)(Bs + (nt * 16 + l15) * 72 + kk * 32 + q * 8);
                acc[0][nt] = __builtin_amdgcn_mfma_f32_16x16x32_bf16(a0, bb, acc[0][nt], 0, 0, 0);
                acc[1][nt] = __builtin_amdgcn_mfma_f32_16x16x32_bf16(a1, bb, acc[1][nt], 0, 0, 0);
            }
        }
    }

    #pragma unroll
    for (int mt = 0; mt < 2; ++mt) {
        const int gm = m0 + wv * 32 + mt * 16 + q * 4;
        #pragma unroll
        for (int nt = 0; nt < 4; ++nt) {
            const int gn = n0 + nt * 16 + l15;
            const float bv = bias[gn];
            #pragma unroll
            for (int r = 0; r < 4; ++r)
                out[(long)(gm + r) * NEMB + gn] = acc[mt][nt][r] + bv;
        }
    }
}

extern "C" void kernel_launch(void* const* d_in, const int* in_sizes, int n_in,
                              void* d_out, int out_size, void* d_ws, size_t ws_size,
                              hipStream_t stream) {
    const float* x      = (const float*)d_in[0];
    const float* w_attn = (const float*)d_in[1];
    const float* pe     = (const float*)d_in[2];
    const float* w_proj = (const float*)d_in[3];
    const float* b_proj = (const float*)d_in[4];
    float* out = (float*)d_out;

    char* base = (char*)d_ws;
    unsigned short* Kb   = (unsigned short*)(base);                        // 4 MB
    unsigned short* Qb   = (unsigned short*)(base + ( 4u << 20));          // 4 MB
    unsigned short* Vt   = (unsigned short*)(base + ( 8u << 20));          // 4 MB
    unsigned short* peb  = (unsigned short*)(base + (12u << 20));          // 1.03 MB
    unsigned short* waT  = (unsigned short*)(base + (14u << 20));          // 384 KB
    unsigned short* wpT  = (unsigned short*)(base + (29u << 19));          // 128 KB @14.5MB
    unsigned short* po   = (unsigned short*)(base + (15u << 20));          // 8 MB
    float*          pl   = (float*)        (base + (23u << 20));           // 512 KB

    prep<<<dim3(592), 256, 0, stream>>>(pe, peb, w_attn, waT, w_proj, wpT);
    qkv_mfma<<<dim3(12, 64), 256, 0, stream>>>(x, waT, Kb, Qb, Vt);
    attn_kernel<<<dim3(32, NH, BB), 256, 0, stream>>>(Kb, Qb, Vt, peb, po, pl);
    proj_mfma<<<dim3(4, 64), 256, 0, stream>>>(po, pl, wpT, b_proj, out);
}

// Round 9
// 164.738 us; speedup vs baseline: 1.1404x; 1.1404x over previous
//
#include <hip/hip_runtime.h>
#include <math.h>

#define BB 4
#define TT 2048
#define TTP 2112   // TT + 64 zero pad rows per head (pe)
#define NEMB 256
#define NH 8
#define HD 32

typedef __attribute__((ext_vector_type(8))) short bf8;   // 8 x bf16 (4 VGPRs)
typedef __attribute__((ext_vector_type(4))) float f4;    // MFMA C/D

static __device__ __forceinline__ unsigned short f2bf(float f) {
    union { float f; unsigned u; } v; v.f = f;
    unsigned r = v.u + 0x7FFF + ((v.u >> 16) & 1);       // RNE
    return (unsigned short)(r >> 16);
}
static __device__ __forceinline__ float bf2f(unsigned short s) {
    union { unsigned u; float f; } v; v.u = ((unsigned)s) << 16;
    return v.f;
}

// DPP cross-lane move within 16-lane rows (VALU pipe)
template <int CTRL>
static __device__ __forceinline__ float dppmv(float x) {
    return __int_as_float(__builtin_amdgcn_mov_dpp(__float_as_int(x), CTRL, 0xF, 0xF, true));
}
static __device__ __forceinline__ float rowsum16(float x) {
    x += dppmv<0xB1>(x);
    x += dppmv<0x4E>(x);
    x += dppmv<0x124>(x);
    x += dppmv<0x128>(x);
    return x;
}

static __device__ __forceinline__ void tcvt_body(const float* __restrict__ src,
                                                 unsigned short* __restrict__ dst,
                                                 int R, int C, int gx, int gy,
                                                 float (*t)[65], int tid) {
    const int c0 = gx * 64, r0 = gy * 64;
    #pragma unroll
    for (int p = 0; p < 4; ++p) {
        const int i = tid + p * 256;
        const int r = i >> 4, c4 = (i & 15) * 4;
        const float4 v = *(const float4*)(src + (long)(r0 + r) * C + c0 + c4);
        t[r][c4] = v.x; t[r][c4+1] = v.y; t[r][c4+2] = v.z; t[r][c4+3] = v.w;
    }
    __syncthreads();
    #pragma unroll
    for (int p = 0; p < 4; ++p) {
        const int i = tid + p * 256;
        const int cr = i >> 4, r4 = (i & 15) * 4;
        ushort4 vv;
        vv.x = f2bf(t[r4+0][cr]); vv.y = f2bf(t[r4+1][cr]);
        vv.z = f2bf(t[r4+2][cr]); vv.w = f2bf(t[r4+3][cr]);
        *(ushort4*)(dst + (long)(c0 + cr) * R + r0 + r4) = vv;
    }
}

// ---------------- Kernel A: qkv GEMM (fp32 A + fp32 B inline-converted) ------
// + rider blocks: pe->bf16 (zero-padded) and w_proj^T (consumed by later
// kernels only, so they can share this launch).
// Q pre-scaled by (1/sqrt(32)) * log2(e) so attention uses raw exp2.
__global__ __launch_bounds__(256) void qkv_mfma(const float* __restrict__ xg,
                                                const float* __restrict__ wa,
                                                const float* __restrict__ pe,
                                                const float* __restrict__ wp,
                                                unsigned short* __restrict__ Kb,
                                                unsigned short* __restrict__ Qb,
                                                unsigned short* __restrict__ Vt,
                                                unsigned short* __restrict__ peb,
                                                unsigned short* __restrict__ wpT) {
    __shared__ unsigned short sm[13824];             // 27648 B (also reused by tcvt)
    const int bx = blockIdx.x;
    const int tid = threadIdx.x;

    if (bx >= 768) {
        if (bx < 1296) {                             // pe -> [8][2112][32] bf16, pad=0
            const int idx4 = (bx - 768) * 256 + tid;
            const int h   = idx4 / 16896;
            const int rem = idx4 - h * 16896;
            const int u   = rem >> 3;
            const int d4  = (rem & 7) * 4;
            ushort4 o = make_ushort4(0, 0, 0, 0);
            if (u < TT) {
                const float4 v = *(const float4*)(pe + ((long)(h * TT + u)) * HD + d4);
                o.x = f2bf(v.x); o.y = f2bf(v.y); o.z = f2bf(v.z); o.w = f2bf(v.w);
            }
            *(ushort4*)(peb + ((long)(h * TTP + u)) * HD + d4) = o;
        } else {                                     // w_proj transpose (16 blocks)
            float (*t)[65] = (float (*)[65])sm;
            const int lo = bx - 1296;
            tcvt_body(wp, wpT, 256, 256, lo % 4, lo / 4, t, tid);
        }
        return;
    }

    unsigned short* As = sm;                         // [128][72]
    unsigned short* Bs = sm + 9216;                  // [64][72]  (n-major, k inner)
    const int wv = tid >> 6, L = tid & 63;
    const int l15 = L & 15, q = L >> 4;
    const int n0 = (bx % 12) * 64;
    const int m0 = (bx / 12) * 128;

    f4 acc[2][4];
    #pragma unroll
    for (int mt = 0; mt < 2; ++mt)
        #pragma unroll
        for (int nt = 0; nt < 4; ++nt) acc[mt][nt] = (f4){0.f,0.f,0.f,0.f};

    for (int kc = 0; kc < 4; ++kc) {
        const int k0 = kc * 64;
        __syncthreads();
        #pragma unroll
        for (int p = 0; p < 4; ++p) {                // A: x fp32 -> bf16, row-major
            const int i = tid + p * 256;
            const int r = i >> 3, c = i & 7;
            const float4 va = *(const float4*)(xg + (long)(m0 + r) * 256 + k0 + c * 8);
            const float4 vb = *(const float4*)(xg + (long)(m0 + r) * 256 + k0 + c * 8 + 4);
            ushort4 lo, hi;
            lo.x = f2bf(va.x); lo.y = f2bf(va.y); lo.z = f2bf(va.z); lo.w = f2bf(va.w);
            hi.x = f2bf(vb.x); hi.y = f2bf(vb.y); hi.z = f2bf(vb.z); hi.w = f2bf(vb.w);
            *(ushort4*)(As + r * 72 + c * 8)     = lo;
            *(ushort4*)(As + r * 72 + c * 8 + 4) = hi;
        }
        #pragma unroll
        for (int p = 0; p < 4; ++p) {                // B: w_attn fp32 [k][n] -> Bs[n][k] bf16
            const int i = tid + p * 256;
            const int kr = i >> 4;                   // 0..63
            const int n4 = (i & 15) * 4;
            const float4 v = *(const float4*)(wa + (long)(k0 + kr) * 768 + n0 + n4);
            Bs[(n4+0) * 72 + kr] = f2bf(v.x);
            Bs[(n4+1) * 72 + kr] = f2bf(v.y);
            Bs[(n4+2) * 72 + kr] = f2bf(v.z);
            Bs[(n4+3) * 72 + kr] = f2bf(v.w);
        }
        __syncthreads();
        #pragma unroll
        for (int kk = 0; kk < 2; ++kk) {
            const bf8 a0 = *(const bf8*)(As + (wv * 32 + l15) * 72 + kk * 32 + q * 8);
            const bf8 a1 = *(const bf8*)(As + (wv * 32 + 16 + l15) * 72 + kk * 32 + q * 8);
            #pragma unroll
            for (int nt = 0; nt < 4; ++nt) {
                const bf8 bb = *(const bf8*)(Bs + (nt * 16 + l15) * 72 + kk * 32 + q * 8);
                acc[0][nt] = __builtin_amdgcn_mfma_f32_16x16x32_bf16(a0, bb, acc[0][nt], 0, 0, 0);
                acc[1][nt] = __builtin_amdgcn_mfma_f32_16x16x32_bf16(a1, bb, acc[1][nt], 0, 0, 0);
            }
        }
    }

    const int sec = n0 >> 8;                         // 0=K,1=Q,2=V
    #pragma unroll
    for (int mt = 0; mt < 2; ++mt) {
        const int gm = m0 + wv * 32 + mt * 16 + q * 4;
        const int b = gm >> 11, tb = gm & 2047;
        #pragma unroll
        for (int nt = 0; nt < 4; ++nt) {
            const int gn = n0 + nt * 16 + l15;
            const int cc = gn & 255, h = cc >> 5, d = cc & 31;
            const long bh = (long)b * NH + h;
            const f4 a = acc[mt][nt];
            if (sec == 2) {
                ushort4 vv;
                vv.x = f2bf(a[0]); vv.y = f2bf(a[1]); vv.z = f2bf(a[2]); vv.w = f2bf(a[3]);
                *(ushort4*)(Vt + (bh * HD + d) * TT + tb) = vv;
            } else if (sec == 1) {
                #pragma unroll
                for (int r = 0; r < 4; ++r)
                    Qb[(bh * TT + tb + r) * HD + d] = f2bf(a[r] * 0.25506655788696527f);
            } else {
                #pragma unroll
                for (int r = 0; r < 4; ++r)
                    Kb[(bh * TT + tb + r) * HD + d] = f2bf(a[r]);
            }
        }
    }
}

// ---------------- Kernel B: flash attention, LDS staging + reg prefetch ------
// Static-max softmax (acc init -16), raw partial O + l per s-split block;
// merge happens in proj's A-staging. Staging loads for iteration jt+2 are
// prefetched into VGPRs during jt's compute phase (hides L2 latency).
__global__ __launch_bounds__(256) void attn_kernel(const unsigned short* __restrict__ Kb,
                                                   const unsigned short* __restrict__ Qb,
                                                   const unsigned short* __restrict__ Vtg,
                                                   const unsigned short* __restrict__ peb,
                                                   unsigned short* __restrict__ po,
                                                   float* __restrict__ pl) {
    __shared__ unsigned short lds[14592];            // 29184 B
    unsigned short* Ks  = lds;                       // [64][40]  K tile
    unsigned short* PEs = lds + 2560;                // [128][40] pe band
    unsigned short* Vts = lds + 7680;                // [32][72]  V^T tile
    unsigned short* Psw = lds + 9984 + (threadIdx.x >> 6) * 1152;  // [16][72] per wave

    const int tid = threadIdx.x;
    const int wv  = tid >> 6;
    const int L   = tid & 63;
    const int l15 = L & 15;
    const int q   = L >> 4;
    const int pair = blockIdx.x >> 1;
    const int sblk = blockIdx.x & 1;
    const int h = blockIdx.y, b = blockIdx.z;
    const long bh = (long)b * NH + h;
    const unsigned short* Kg = Kb  + bh * TT * HD;
    const unsigned short* Qg = Qb  + bh * TT * HD;
    const unsigned short* Vg = Vtg + bh * HD * TT;
    const unsigned short* Pg = peb + (long)h * TTP * HD;

    const int krow = tid >> 2, kc = tid & 3;         // K staging split
    const int vrow = tid >> 3, vc = tid & 7;         // V^T staging split
    const int prow = tid >> 2, pc = tid & 3;         // pe staging split
    const f4 z4 = {0.f, 0.f, 0.f, 0.f};
    const f4 m4 = {-16.f, -16.f, -16.f, -16.f};      // static softmax max

    // hoisted skew-gather controls (per r): source lane + perm half-select
    int saddr[4]; unsigned psel[4];
    #pragma unroll
    for (int r = 0; r < 4; ++r) {
        const int tcol = l15 + 15 - 4 * q - r;       // 0..30
        saddr[r] = ((q << 4) | (tcol & 15)) << 2;
        psel[r]  = (tcol < 16) ? 0x01000C0Cu : 0x03020C0Cu;
    }

    for (int half = 0; half < 2; ++half) {
        const int itile = half ? 31 - pair : pair;
        const int t0 = itile * 64;

        const bf8 aq = *(const bf8*)(Qg + (t0 + wv * 16 + l15) * HD + q * 8);
        f4 o0 = z4, o1 = z4;
        float l_st[4] = {0.f, 0.f, 0.f, 0.f};

        // prefetch first iteration's staging into regs
        bf8 rK, rV, rP0, rP1;
        {
            const int s0 = sblk * 64;
            const int ub = TT - 64 - t0 + s0;
            rK  = *(const bf8*)(Kg + (s0 + krow) * HD + kc * 8);
            rV  = *(const bf8*)(Vg + vrow * TT + s0 + vc * 8);
            rP0 = *(const bf8*)(Pg + (long)(ub + prow) * HD + pc * 8);
            rP1 = *(const bf8*)(Pg + (long)(ub + 64 + prow) * HD + pc * 8);
        }

        for (int jt = sblk; jt <= itile; jt += 2) {
            __syncthreads();                         // prior reads done
            *(bf8*)(Ks  + krow * 40 + kc * 8) = rK;
            *(bf8*)(Vts + vrow * 72 + vc * 8) = rV;
            *(bf8*)(PEs + prow * 40 + pc * 8) = rP0;
            *(bf8*)(PEs + (64 + prow) * 40 + pc * 8) = rP1;
            __syncthreads();

            if (jt + 2 <= itile) {                   // prefetch next iteration
                const int s0n = (jt + 2) * 64;
                const int ubn = TT - 64 - t0 + s0n;
                rK  = *(const bf8*)(Kg + (s0n + krow) * HD + kc * 8);
                rV  = *(const bf8*)(Vg + vrow * TT + s0n + vc * 8);
                rP0 = *(const bf8*)(Pg + (long)(ubn + prow) * HD + pc * 8);
                rP1 = *(const bf8*)(Pg + (long)(ubn + 64 + prow) * HD + pc * 8);
            }

            f4 sa[4], ra[5];
            #pragma unroll
            for (int nt = 0; nt < 4; ++nt) {
                const bf8 bk = *(const bf8*)(Ks + (nt * 16 + l15) * 40 + q * 8);
                sa[nt] = __builtin_amdgcn_mfma_f32_16x16x32_bf16(aq, bk, m4, 0, 0, 0);
            }
            const int pebase = 48 - 16 * wv;
            #pragma unroll
            for (int nt = 0; nt < 5; ++nt) {
                const bf8 bp = *(const bf8*)(PEs + (pebase + nt * 16 + l15) * 40 + q * 8);
                ra[nt] = __builtin_amdgcn_mfma_f32_16x16x32_bf16(aq, bp, z4, 0, 0, 0);
            }

            // ---- skew gather: v_perm pack + bpermute + v_perm select ----
            #pragma unroll
            for (int nb = 0; nb < 4; ++nb) {
                #pragma unroll
                for (int r = 0; r < 4; ++r) {
                    const unsigned packed = __builtin_amdgcn_perm(
                        (unsigned)__float_as_int(ra[nb + 1][r]),
                        (unsigned)__float_as_int(ra[nb][r]), 0x07060302u);
                    const int v = __builtin_amdgcn_ds_bpermute(saddr[r], (int)packed);
                    const unsigned sel = __builtin_amdgcn_perm((unsigned)v, (unsigned)v, psel[r]);
                    sa[nb][r] += __int_as_float((int)sel);
                }
            }

            if (jt == itile) {                       // causal mask (diagonal tile)
                #pragma unroll
                for (int nb = 0; nb < 4; ++nb)
                    #pragma unroll
                    for (int r = 0; r < 4; ++r) {
                        const int s_l = nb * 16 + l15;
                        const int t_l = wv * 16 + 4 * q + r;
                        if (s_l > t_l) sa[nb][r] = -1e30f;
                    }
            }

            // ---- static-max softmax: p = exp2(sa); accumulate l per lane ----
            #pragma unroll
            for (int r = 0; r < 4; ++r) {
                #pragma unroll
                for (int nb = 0; nb < 4; ++nb) {
                    const float p = exp2f(sa[nb][r]);
                    l_st[r] += p;
                    const unsigned pu = (unsigned)__float_as_int(p);
                    Psw[(4 * q + r) * 72 + nb * 16 + l15] =
                        (unsigned short)((pu + 0x8000u) >> 16);
                }
            }

            // ---- PV: O += P @ V ----
            #pragma unroll
            for (int ks = 0; ks < 2; ++ks) {
                const bf8 ap  = *(const bf8*)(Psw + l15 * 72 + ks * 32 + q * 8);
                const bf8 bv0 = *(const bf8*)(Vts + l15 * 72 + ks * 32 + q * 8);
                const bf8 bv1 = *(const bf8*)(Vts + (16 + l15) * 72 + ks * 32 + q * 8);
                o0 = __builtin_amdgcn_mfma_f32_16x16x32_bf16(ap, bv0, o0, 0, 0, 0);
                o1 = __builtin_amdgcn_mfma_f32_16x16x32_bf16(ap, bv1, o1, 0, 0, 0);
            }
        }

        // ---- epilogue: raw partial O (bf16) + row l ----
        const long pt = (bh * 32 + itile) * 2 + sblk;
        unsigned short* pob = po + pt * 2048;
        #pragma unroll
        for (int r = 0; r < 4; ++r) {
            const int row = wv * 16 + 4 * q + r;
            pob[row * 32 + l15]      = f2bf(o0[r]);
            pob[row * 32 + 16 + l15] = f2bf(o1[r]);
            const float ls = rowsum16(l_st[r]);
            if (l15 == 0) pl[pt * 64 + row] = ls;
        }
    }
}

// ---------------- Kernel C: proj GEMM + fused s-split merge + bias -----------
__global__ __launch_bounds__(256) void proj_mfma(const unsigned short* __restrict__ po,
                                                 const float* __restrict__ pl,
                                                 const unsigned short* __restrict__ Bg,
                                                 const float* __restrict__ bias,
                                                 float* __restrict__ out) {
    __shared__ unsigned short sm[13824];
    unsigned short* As = sm;                         // [128][72]
    unsigned short* Bs = sm + 9216;                  // [64][72]
    const int tid = threadIdx.x;
    const int wv = tid >> 6, L = tid & 63;
    const int l15 = L & 15, q = L >> 4;
    const int n0 = blockIdx.x * 64;
    const int m0 = blockIdx.y * 128;

    f4 acc[2][4];
    #pragma unroll
    for (int mt = 0; mt < 2; ++mt)
        #pragma unroll
        for (int nt = 0; nt < 4; ++nt) acc[mt][nt] = (f4){0.f,0.f,0.f,0.f};

    for (int kc = 0; kc < 4; ++kc) {
        const int k0 = kc * 64;
        __syncthreads();
        #pragma unroll
        for (int p = 0; p < 4; ++p) {
            const int i = tid + p * 256;
            const int r = i >> 3, c = i & 7;
            const int gm = m0 + r;
            const int bloc = gm >> 11, t = gm & 2047;
            const int k = k0 + c * 8;
            const int hh = k >> 5, d0 = k & 31;
            const int tile = t >> 6, row = t & 63;
            const long pt0 = ((long)(bloc * NH + hh) * 32 + tile) * 2;
            const float l0 = pl[pt0 * 64 + row];
            const float l1 = pl[pt0 * 64 + 64 + row];
            const float inv = 1.0f / (l0 + l1);
            const unsigned short* p0 = po + pt0 * 2048 + row * 32 + d0;
            const unsigned short* p1 = p0 + 2048;
            const ushort4 a0 = *(const ushort4*)p0;
            const ushort4 a1 = *(const ushort4*)(p0 + 4);
            const ushort4 c0 = *(const ushort4*)p1;
            const ushort4 c1 = *(const ushort4*)(p1 + 4);
            ushort4 o0, o1;
            o0.x = f2bf((bf2f(a0.x) + bf2f(c0.x)) * inv);
            o0.y = f2bf((bf2f(a0.y) + bf2f(c0.y)) * inv);
            o0.z = f2bf((bf2f(a0.z) + bf2f(c0.z)) * inv);
            o0.w = f2bf((bf2f(a0.w) + bf2f(c0.w)) * inv);
            o1.x = f2bf((bf2f(a1.x) + bf2f(c1.x)) * inv);
            o1.y = f2bf((bf2f(a1.y) + bf2f(c1.y)) * inv);
            o1.z = f2bf((bf2f(a1.z) + bf2f(c1.z)) * inv);
            o1.w = f2bf((bf2f(a1.w) + bf2f(c1.w)) * inv);
            *(ushort4*)(As + r * 72 + c * 8)     = o0;
            *(ushort4*)(As + r * 72 + c * 8 + 4) = o1;
        }
        #pragma unroll
        for (int p = 0; p < 2; ++p) {
            const int i = tid + p * 256;
            const int r = i >> 3, c = i & 7;
            *(bf8*)(Bs + r * 72 + c * 8) = *(const bf8*)(Bg + (long)(n0 + r) * 256 + k0 + c * 8);
        }
        __syncthreads();
        #pragma unroll
        for (int kk = 0; kk < 2; ++kk) {
            const bf8 a0 = *(const bf8*)(As + (wv * 32 + l15) * 72 + kk * 32 + q * 8);
            const bf8 a1 = *(const bf8*)(As + (wv * 32 + 16 + l15) * 72 + kk * 32 + q * 8);
            #pragma unroll
            for (int nt = 0; nt < 4; ++nt) {
                const bf8 bb = *(const bf8*)(Bs + (nt * 16 + l15) * 72 + kk * 32 + q * 8);
                acc[0][nt] = __builtin_amdgcn_mfma_f32_16x16x32_bf16(a0, bb, acc[0][nt], 0, 0, 0);
                acc[1][nt] = __builtin_amdgcn_mfma_f32_16x16x32_bf16(a1, bb, acc[1][nt], 0, 0, 0);
            }
        }
    }

    #pragma unroll
    for (int mt = 0; mt < 2; ++mt) {
        const int gm = m0 + wv * 32 + mt * 16 + q * 4;
        #pragma unroll
        for (int nt = 0; nt < 4; ++nt) {
            const int gn = n0 + nt * 16 + l15;
            const float bv = bias[gn];
            #pragma unroll
            for (int r = 0; r < 4; ++r)
                out[(long)(gm + r) * NEMB + gn] = acc[mt][nt][r] + bv;
        }
    }
}

extern "C" void kernel_launch(void* const* d_in, const int* in_sizes, int n_in,
                              void* d_out, int out_size, void* d_ws, size_t ws_size,
                              hipStream_t stream) {
    const float* x      = (const float*)d_in[0];
    const float* w_attn = (const float*)d_in[1];
    const float* pe     = (const float*)d_in[2];
    const float* w_proj = (const float*)d_in[3];
    const float* b_proj = (const float*)d_in[4];
    float* out = (float*)d_out;

    char* base = (char*)d_ws;
    unsigned short* Kb   = (unsigned short*)(base);                        // 4 MB
    unsigned short* Qb   = (unsigned short*)(base + ( 4u << 20));          // 4 MB
    unsigned short* Vt   = (unsigned short*)(base + ( 8u << 20));          // 4 MB
    unsigned short* peb  = (unsigned short*)(base + (12u << 20));          // 1.03 MB
    unsigned short* wpT  = (unsigned short*)(base + (14u << 20));          // 128 KB
    unsigned short* po   = (unsigned short*)(base + (15u << 20));          // 8 MB
    float*          pl   = (float*)        (base + (23u << 20));           // 512 KB

    qkv_mfma<<<dim3(1312), 256, 0, stream>>>(x, w_attn, pe, w_proj, Kb, Qb, Vt, peb, wpT);
    attn_kernel<<<dim3(32, NH, BB), 256, 0, stream>>>(Kb, Qb, Vt, peb, po, pl);
    proj_mfma<<<dim3(4, 64), 256, 0, stream>>>(po, pl, wpT, b_proj, out);
}

// Round 10
// 162.629 us; speedup vs baseline: 1.1551x; 1.0130x over previous
//
#include <hip/hip_runtime.h>
#include <math.h>

#define BB 4
#define TT 2048
#define TTP 2176   // TT + 128 zero pad rows per head (pe)
#define NEMB 256
#define NH 8
#define HD 32

typedef __attribute__((ext_vector_type(8))) short bf8;   // 8 x bf16 (4 VGPRs)
typedef __attribute__((ext_vector_type(4))) float f4;    // MFMA C/D

static __device__ __forceinline__ unsigned short f2bf(float f) {
    union { float f; unsigned u; } v; v.f = f;
    unsigned r = v.u + 0x7FFF + ((v.u >> 16) & 1);       // RNE
    return (unsigned short)(r >> 16);
}
static __device__ __forceinline__ float bf2f(unsigned short s) {
    union { unsigned u; float f; } v; v.u = ((unsigned)s) << 16;
    return v.f;
}

// DPP cross-lane move within 16-lane rows (VALU pipe)
template <int CTRL>
static __device__ __forceinline__ float dppmv(float x) {
    return __int_as_float(__builtin_amdgcn_mov_dpp(__float_as_int(x), CTRL, 0xF, 0xF, true));
}
static __device__ __forceinline__ float rowsum16(float x) {
    x += dppmv<0xB1>(x);
    x += dppmv<0x4E>(x);
    x += dppmv<0x124>(x);
    x += dppmv<0x128>(x);
    return x;
}

// ---------------- prep: pe->bf16 (+128 zero pad), w_attn^T, w_proj^T ---------
static __device__ __forceinline__ void tcvt_body(const float* __restrict__ src,
                                                 unsigned short* __restrict__ dst,
                                                 int R, int C, int gx, int gy,
                                                 float (*t)[65], int tid) {
    const int c0 = gx * 64, r0 = gy * 64;
    #pragma unroll
    for (int p = 0; p < 4; ++p) {
        const int i = tid + p * 256;
        const int r = i >> 4, c4 = (i & 15) * 4;
        const float4 v = *(const float4*)(src + (long)(r0 + r) * C + c0 + c4);
        t[r][c4] = v.x; t[r][c4+1] = v.y; t[r][c4+2] = v.z; t[r][c4+3] = v.w;
    }
    __syncthreads();
    #pragma unroll
    for (int p = 0; p < 4; ++p) {
        const int i = tid + p * 256;
        const int cr = i >> 4, r4 = (i & 15) * 4;
        ushort4 vv;
        vv.x = f2bf(t[r4+0][cr]); vv.y = f2bf(t[r4+1][cr]);
        vv.z = f2bf(t[r4+2][cr]); vv.w = f2bf(t[r4+3][cr]);
        *(ushort4*)(dst + (long)(c0 + cr) * R + r0 + r4) = vv;
    }
}

__global__ __launch_bounds__(256) void prep(const float* __restrict__ pe,
                                            unsigned short* __restrict__ peb,
                                            const float* __restrict__ wa,
                                            unsigned short* __restrict__ waT,
                                            const float* __restrict__ wp,
                                            unsigned short* __restrict__ wpT) {
    __shared__ float t[64][65];
    const int bx = blockIdx.x, tid = threadIdx.x;
    if (bx < 544) {                              // pe -> [8][2176][32] bf16, pad=0
        const int idx4 = bx * 256 + tid;         // ushort4 granules [8][2176][8]
        const int h   = idx4 / 17408;
        const int rem = idx4 - h * 17408;
        const int u   = rem >> 3;
        const int d4  = (rem & 7) * 4;
        ushort4 o = make_ushort4(0, 0, 0, 0);
        if (u < TT) {
            const float4 v = *(const float4*)(pe + ((long)(h * TT + u)) * HD + d4);
            o.x = f2bf(v.x); o.y = f2bf(v.y); o.z = f2bf(v.z); o.w = f2bf(v.w);
        }
        *(ushort4*)(peb + ((long)(h * TTP + u)) * HD + d4) = o;
    } else if (bx < 592) {
        const int lo = bx - 544;                 // w_attn [256][768] -> [768][256]
        tcvt_body(wa, waT, 256, 768, lo % 12, lo / 12, t, tid);
    } else {
        const int lo = bx - 592;                 // w_proj transpose
        tcvt_body(wp, wpT, 256, 256, lo % 4, lo / 4, t, tid);
    }
}

// ---------------- Kernel A: MFMA qkv GEMM, fp32 A inline-converted -----------
// Q pre-scaled by (1/sqrt(32)) * log2(e); V stored sigma-permuted per 64-block:
// col sigma(t) = 4*(t&15) + ((t>>4)&3)  (matches attn's P/V shared k-order).
__global__ __launch_bounds__(256) void qkv_mfma(const float* __restrict__ xg,
                                                const unsigned short* __restrict__ Bg,
                                                unsigned short* __restrict__ Kb,
                                                unsigned short* __restrict__ Qb,
                                                unsigned short* __restrict__ Vt) {
    __shared__ unsigned short sm[13824];             // 27648 B
    unsigned short* As = sm;                         // [128][72]
    unsigned short* Bs = sm + 9216;                  // [64][72]
    const int tid = threadIdx.x;
    const int wv = tid >> 6, L = tid & 63;
    const int l15 = L & 15, q = L >> 4;
    const int n0 = blockIdx.x * 64;
    const int m0 = blockIdx.y * 128;

    f4 acc[2][4];
    #pragma unroll
    for (int mt = 0; mt < 2; ++mt)
        #pragma unroll
        for (int nt = 0; nt < 4; ++nt) acc[mt][nt] = (f4){0.f,0.f,0.f,0.f};

    for (int kc = 0; kc < 4; ++kc) {
        const int k0 = kc * 64;
        __syncthreads();
        #pragma unroll
        for (int p = 0; p < 4; ++p) {
            const int i = tid + p * 256;
            const int r = i >> 3, c = i & 7;
            const float4 va = *(const float4*)(xg + (long)(m0 + r) * 256 + k0 + c * 8);
            const float4 vb = *(const float4*)(xg + (long)(m0 + r) * 256 + k0 + c * 8 + 4);
            ushort4 lo, hi;
            lo.x = f2bf(va.x); lo.y = f2bf(va.y); lo.z = f2bf(va.z); lo.w = f2bf(va.w);
            hi.x = f2bf(vb.x); hi.y = f2bf(vb.y); hi.z = f2bf(vb.z); hi.w = f2bf(vb.w);
            *(ushort4*)(As + r * 72 + c * 8)     = lo;
            *(ushort4*)(As + r * 72 + c * 8 + 4) = hi;
        }
        #pragma unroll
        for (int p = 0; p < 2; ++p) {
            const int i = tid + p * 256;
            const int r = i >> 3, c = i & 7;
            *(bf8*)(Bs + r * 72 + c * 8) = *(const bf8*)(Bg + (long)(n0 + r) * 256 + k0 + c * 8);
        }
        __syncthreads();
        #pragma unroll
        for (int kk = 0; kk < 2; ++kk) {
            const bf8 a0 = *(const bf8*)(As + (wv * 32 + l15) * 72 + kk * 32 + q * 8);
            const bf8 a1 = *(const bf8*)(As + (wv * 32 + 16 + l15) * 72 + kk * 32 + q * 8);
            #pragma unroll
            for (int nt = 0; nt < 4; ++nt) {
                const bf8 bb = *(const bf8*)(Bs + (nt * 16 + l15) * 72 + kk * 32 + q * 8);
                acc[0][nt] = __builtin_amdgcn_mfma_f32_16x16x32_bf16(a0, bb, acc[0][nt], 0, 0, 0);
                acc[1][nt] = __builtin_amdgcn_mfma_f32_16x16x32_bf16(a1, bb, acc[1][nt], 0, 0, 0);
            }
        }
    }

    const int sec = n0 >> 8;                         // 0=K,1=Q,2=V
    #pragma unroll
    for (int mt = 0; mt < 2; ++mt) {
        const int gm = m0 + wv * 32 + mt * 16 + q * 4;
        const int b = gm >> 11, tb = gm & 2047;
        #pragma unroll
        for (int nt = 0; nt < 4; ++nt) {
            const int gn = n0 + nt * 16 + l15;
            const int cc = gn & 255, h = cc >> 5, d = cc & 31;
            const long bh = (long)b * NH + h;
            const f4 a = acc[mt][nt];
            if (sec == 2) {
                #pragma unroll
                for (int r = 0; r < 4; ++r) {
                    const int t = tb + r;
                    const int ts = (t & ~63) | (((t & 15) << 2) | ((t >> 4) & 3));
                    Vt[(bh * HD + d) * TT + ts] = f2bf(a[r]);
                }
            } else if (sec == 1) {
                #pragma unroll
                for (int r = 0; r < 4; ++r)
                    Qb[(bh * TT + tb + r) * HD + d] = f2bf(a[r] * 0.25506655788696527f);
            } else {
                #pragma unroll
                for (int r = 0; r < 4; ++r)
                    Kb[(bh * TT + tb + r) * HD + d] = f2bf(a[r]);
            }
        }
    }
}

// ---------------- Kernel B: flash attention, 128-t tiles, sigma-packed P -----
// 4 waves x 2 sequential 16-row strips; K/V/pe staged once per 64-s tile and
// shared. Static-max softmax (acc init -16); P stored via sigma s-permutation
// so each lane writes one b64 per row (cols 4*l15..+3 = nb). V pre-permuted.
__global__ __launch_bounds__(256) void attn_kernel(const unsigned short* __restrict__ Kb,
                                                   const unsigned short* __restrict__ Qb,
                                                   const unsigned short* __restrict__ Vtg,
                                                   const unsigned short* __restrict__ peb,
                                                   unsigned short* __restrict__ po,
                                                   float* __restrict__ pl) {
    __shared__ unsigned short lds[17152];            // 34304 B
    unsigned short* Ks  = lds;                       // [64][40]
    unsigned short* PEs = lds + 2560;                // [192][40]
    unsigned short* Vts = lds + 10240;               // [32][72]
    unsigned short* Psw = lds + 12544 + (threadIdx.x >> 6) * 1152;  // [16][72]/wave

    const int tid = threadIdx.x;
    const int wv  = tid >> 6;
    const int L   = tid & 63;
    const int l15 = L & 15;
    const int q   = L >> 4;
    const int pair = blockIdx.x >> 1;
    const int sblk = blockIdx.x & 1;
    const int h = blockIdx.y, b = blockIdx.z;
    const long bh = (long)b * NH + h;
    const unsigned short* Kg = Kb  + bh * TT * HD;
    const unsigned short* Qg = Qb  + bh * TT * HD;
    const unsigned short* Vg = Vtg + bh * HD * TT;
    const unsigned short* Pg = peb + (long)h * TTP * HD;

    const int krow = tid >> 2, kc = tid & 3;         // K staging split
    const int vrow = tid >> 3, vc = tid & 7;         // V staging split
    const f4 z4 = {0.f, 0.f, 0.f, 0.f};
    const f4 m4 = {-16.f, -16.f, -16.f, -16.f};      // static softmax max

    int saddr[4]; unsigned psel[4];
    #pragma unroll
    for (int r = 0; r < 4; ++r) {
        const int tcol = l15 + 15 - 4 * q - r;       // 0..30
        saddr[r] = ((q << 4) | (tcol & 15)) << 2;
        psel[r]  = (tcol < 16) ? 0x01000C0Cu : 0x03020C0Cu;
    }

    for (int half = 0; half < 2; ++half) {
        const int itile = half ? 15 - pair : pair;
        const int t0 = itile * 128;

        bf8 aq[2];
        #pragma unroll
        for (int mf = 0; mf < 2; ++mf)
            aq[mf] = *(const bf8*)(Qg + (t0 + wv * 32 + mf * 16 + l15) * HD + q * 8);
        f4 o[2][2];
        o[0][0] = z4; o[0][1] = z4; o[1][0] = z4; o[1][1] = z4;
        float l_st[2][4] = {{0.f,0.f,0.f,0.f},{0.f,0.f,0.f,0.f}};

        const int jtmax = 2 * itile + 1;
        for (int jt = sblk; jt <= jtmax; jt += 2) {
            const int s0 = jt * 64;
            const int ub0 = TT - 128 - t0 + s0;      // pe band base (pad rows = 0)
            __syncthreads();
            *(bf8*)(Ks  + krow * 40 + kc * 8) = *(const bf8*)(Kg + (s0 + krow) * HD + kc * 8);
            *(bf8*)(Vts + vrow * 72 + vc * 8) = *(const bf8*)(Vg + vrow * TT + s0 + vc * 8);
            #pragma unroll
            for (int kk = 0; kk < 3; ++kk) {
                const int i  = tid + kk * 256;
                const int pr = i >> 2, pc = i & 3;
                *(bf8*)(PEs + pr * 40 + pc * 8) = *(const bf8*)(Pg + (long)(ub0 + pr) * HD + pc * 8);
            }
            __syncthreads();

            bf8 bk[4], bva[2], bvb[2];
            #pragma unroll
            for (int nt = 0; nt < 4; ++nt)
                bk[nt] = *(const bf8*)(Ks + (nt * 16 + l15) * 40 + q * 8);
            #pragma unroll
            for (int ks = 0; ks < 2; ++ks) {
                bva[ks] = *(const bf8*)(Vts + l15 * 72 + ks * 32 + q * 8);
                bvb[ks] = *(const bf8*)(Vts + (16 + l15) * 72 + ks * 32 + q * 8);
            }

            #pragma unroll
            for (int mf = 0; mf < 2; ++mf) {
                f4 sa[4], ra[5];
                #pragma unroll
                for (int nt = 0; nt < 4; ++nt)
                    sa[nt] = __builtin_amdgcn_mfma_f32_16x16x32_bf16(aq[mf], bk[nt], m4, 0, 0, 0);
                const int pebs = 112 - wv * 32 - mf * 16;
                #pragma unroll
                for (int nt = 0; nt < 5; ++nt) {
                    const bf8 bp = *(const bf8*)(PEs + (pebs + nt * 16 + l15) * 40 + q * 8);
                    ra[nt] = __builtin_amdgcn_mfma_f32_16x16x32_bf16(aq[mf], bp, z4, 0, 0, 0);
                }

                // skew gather: v_perm pack + bpermute + v_perm select
                #pragma unroll
                for (int nb = 0; nb < 4; ++nb) {
                    #pragma unroll
                    for (int r = 0; r < 4; ++r) {
                        const unsigned packed = __builtin_amdgcn_perm(
                            (unsigned)__float_as_int(ra[nb + 1][r]),
                            (unsigned)__float_as_int(ra[nb][r]), 0x07060302u);
                        const int v = __builtin_amdgcn_ds_bpermute(saddr[r], (int)packed);
                        const unsigned sel = __builtin_amdgcn_perm((unsigned)v, (unsigned)v, psel[r]);
                        sa[nb][r] += __int_as_float((int)sel);
                    }
                }

                if (s0 + 63 > t0 + wv * 32 + mf * 16) {      // causal mask
                    #pragma unroll
                    for (int nb = 0; nb < 4; ++nb)
                        #pragma unroll
                        for (int r = 0; r < 4; ++r) {
                            const int s_l = s0 + nb * 16 + l15;
                            const int t_l = t0 + wv * 32 + mf * 16 + 4 * q + r;
                            if (s_l > t_l) sa[nb][r] = -1e30f;
                        }
                }

                // static-max softmax; P packed b64 at sigma-cols 4*l15..+3
                #pragma unroll
                for (int r = 0; r < 4; ++r) {
                    const float p0 = exp2f(sa[0][r]);
                    const float p1 = exp2f(sa[1][r]);
                    const float p2 = exp2f(sa[2][r]);
                    const float p3 = exp2f(sa[3][r]);
                    l_st[mf][r] += (p0 + p1) + (p2 + p3);
                    const unsigned a0 = (unsigned)__float_as_int(p0) + 0x8000u;
                    const unsigned a1 = (unsigned)__float_as_int(p1) + 0x8000u;
                    const unsigned a2 = (unsigned)__float_as_int(p2) + 0x8000u;
                    const unsigned a3 = (unsigned)__float_as_int(p3) + 0x8000u;
                    uint2 w;
                    w.x = __builtin_amdgcn_perm(a1, a0, 0x07060302u);
                    w.y = __builtin_amdgcn_perm(a3, a2, 0x07060302u);
                    *(uint2*)(Psw + (4 * q + r) * 72 + 4 * l15) = w;
                }

                // PV (k-axis in shared sigma order)
                #pragma unroll
                for (int ks = 0; ks < 2; ++ks) {
                    const bf8 ap = *(const bf8*)(Psw + l15 * 72 + ks * 32 + q * 8);
                    o[mf][0] = __builtin_amdgcn_mfma_f32_16x16x32_bf16(ap, bva[ks], o[mf][0], 0, 0, 0);
                    o[mf][1] = __builtin_amdgcn_mfma_f32_16x16x32_bf16(ap, bvb[ks], o[mf][1], 0, 0, 0);
                }
            }
        }

        // epilogue: raw partial O (bf16) + row l
        const long pt = (bh * 16 + itile) * 2 + sblk;
        unsigned short* pob = po + pt * 4096;
        #pragma unroll
        for (int mf = 0; mf < 2; ++mf)
            #pragma unroll
            for (int r = 0; r < 4; ++r) {
                const int row = wv * 32 + mf * 16 + 4 * q + r;
                pob[row * 32 + l15]      = f2bf(o[mf][0][r]);
                pob[row * 32 + 16 + l15] = f2bf(o[mf][1][r]);
                const float ls = rowsum16(l_st[mf][r]);
                if (l15 == 0) pl[pt * 128 + row] = ls;
            }
    }
}

// ---------------- Kernel C: proj GEMM + fused s-split merge + bias -----------
__global__ __launch_bounds__(256) void proj_mfma(const unsigned short* __restrict__ po,
                                                 const float* __restrict__ pl,
                                                 const unsigned short* __restrict__ Bg,
                                                 const float* __restrict__ bias,
                                                 float* __restrict__ out) {
    __shared__ unsigned short sm[13824];
    unsigned short* As = sm;                         // [128][72]
    unsigned short* Bs = sm + 9216;                  // [64][72]
    const int tid = threadIdx.x;
    const int wv = tid >> 6, L = tid & 63;
    const int l15 = L & 15, q = L >> 4;
    const int n0 = blockIdx.x * 64;
    const int m0 = blockIdx.y * 128;

    f4 acc[2][4];
    #pragma unroll
    for (int mt = 0; mt < 2; ++mt)
        #pragma unroll
        for (int nt = 0; nt < 4; ++nt) acc[mt][nt] = (f4){0.f,0.f,0.f,0.f};

    for (int kc = 0; kc < 4; ++kc) {
        const int k0 = kc * 64;
        __syncthreads();
        #pragma unroll
        for (int p = 0; p < 4; ++p) {
            const int i = tid + p * 256;
            const int r = i >> 3, c = i & 7;
            const int gm = m0 + r;
            const int bloc = gm >> 11, t = gm & 2047;
            const int k = k0 + c * 8;
            const int hh = k >> 5, d0 = k & 31;
            const int tile = t >> 7, row = t & 127;
            const long pt0 = ((long)(bloc * NH + hh) * 16 + tile) * 2;
            const float l0 = pl[pt0 * 128 + row];
            const float l1 = pl[pt0 * 128 + 128 + row];
            const float inv = 1.0f / (l0 + l1);
            const unsigned short* p0 = po + pt0 * 4096 + row * 32 + d0;
            const unsigned short* p1 = p0 + 4096;
            const ushort4 a0 = *(const ushort4*)p0;
            const ushort4 a1 = *(const ushort4*)(p0 + 4);
            const ushort4 c0 = *(const ushort4*)p1;
            const ushort4 c1 = *(const ushort4*)(p1 + 4);
            ushort4 o0, o1;
            o0.x = f2bf((bf2f(a0.x) + bf2f(c0.x)) * inv);
            o0.y = f2bf((bf2f(a0.y) + bf2f(c0.y)) * inv);
            o0.z = f2bf((bf2f(a0.z) + bf2f(c0.z)) * inv);
            o0.w = f2bf((bf2f(a0.w) + bf2f(c0.w)) * inv);
            o1.x = f2bf((bf2f(a1.x) + bf2f(c1.x)) * inv);
            o1.y = f2bf((bf2f(a1.y) + bf2f(c1.y)) * inv);
            o1.z = f2bf((bf2f(a1.z) + bf2f(c1.z)) * inv);
            o1.w = f2bf((bf2f(a1.w) + bf2f(c1.w)) * inv);
            *(ushort4*)(As + r * 72 + c * 8)     = o0;
            *(ushort4*)(As + r * 72 + c * 8 + 4) = o1;
        }
        #pragma unroll
        for (int p = 0; p < 2; ++p) {
            const int i = tid + p * 256;
            const int r = i >> 3, c = i & 7;
            *(bf8*)(Bs + r * 72 + c * 8) = *(const bf8*)(Bg + (long)(n0 + r) * 256 + k0 + c * 8);
        }
        __syncthreads();
        #pragma unroll
        for (int kk = 0; kk < 2; ++kk) {
            const bf8 a0 = *(const bf8*)(As + (wv * 32 + l15) * 72 + kk * 32 + q * 8);
            const bf8 a1 = *(const bf8*)(As + (wv * 32 + 16 + l15) * 72 + kk * 32 + q * 8);
            #pragma unroll
            for (int nt = 0; nt < 4; ++nt) {
                const bf8 bb = *(const bf8*)(Bs + (nt * 16 + l15) * 72 + kk * 32 + q * 8);
                acc[0][nt] = __builtin_amdgcn_mfma_f32_16x16x32_bf16(a0, bb, acc[0][nt], 0, 0, 0);
                acc[1][nt] = __builtin_amdgcn_mfma_f32_16x16x32_bf16(a1, bb, acc[1][nt], 0, 0, 0);
            }
        }
    }

    #pragma unroll
    for (int mt = 0; mt < 2; ++mt) {
        const int gm = m0 + wv * 32 + mt * 16 + q * 4;
        #pragma unroll
        for (int nt = 0; nt < 4; ++nt) {
            const int gn = n0 + nt * 16 + l15;
            const float bv = bias[gn];
            #pragma unroll
            for (int r = 0; r < 4; ++r)
                out[(long)(gm + r) * NEMB + gn] = acc[mt][nt][r] + bv;
        }
    }
}

extern "C" void kernel_launch(void* const* d_in, const int* in_sizes, int n_in,
                              void* d_out, int out_size, void* d_ws, size_t ws_size,
                              hipStream_t stream) {
    const float* x      = (const float*)d_in[0];
    const float* w_attn = (const float*)d_in[1];
    const float* pe     = (const float*)d_in[2];
    const float* w_proj = (const float*)d_in[3];
    const float* b_proj = (const float*)d_in[4];
    float* out = (float*)d_out;

    char* base = (char*)d_ws;
    unsigned short* Kb   = (unsigned short*)(base);                        // 4 MB
    unsigned short* Qb   = (unsigned short*)(base + ( 4u << 20));          // 4 MB
    unsigned short* Vt   = (unsigned short*)(base + ( 8u << 20));          // 4 MB
    unsigned short* peb  = (unsigned short*)(base + (12u << 20));          // 1.06 MB
    unsigned short* waT  = (unsigned short*)(base + (14u << 20));          // 384 KB
    unsigned short* wpT  = (unsigned short*)(base + (29u << 19));          // 128 KB @14.5MB
    unsigned short* po   = (unsigned short*)(base + (15u << 20));          // 8 MB
    float*          pl   = (float*)        (base + (23u << 20));           // 512 KB

    prep<<<dim3(608), 256, 0, stream>>>(pe, peb, w_attn, waT, w_proj, wpT);
    qkv_mfma<<<dim3(12, 64), 256, 0, stream>>>(x, waT, Kb, Qb, Vt);
    attn_kernel<<<dim3(16, NH, BB), 256, 0, stream>>>(Kb, Qb, Vt, peb, po, pl);
    proj_mfma<<<dim3(4, 64), 256, 0, stream>>>(po, pl, wpT, b_proj, out);
}

// Round 11
// 158.098 us; speedup vs baseline: 1.1882x; 1.0287x over previous
//
#include <hip/hip_runtime.h>
#include <math.h>

#define BB 4
#define TT 2048
#define TTP 2176   // TT + 128 zero pad rows per head (pe)
#define NEMB 256
#define NH 8
#define HD 32

typedef __attribute__((ext_vector_type(8))) short bf8;   // 8 x bf16 (4 VGPRs)
typedef __attribute__((ext_vector_type(4))) float f4;    // MFMA C/D

static __device__ __forceinline__ unsigned short f2bf(float f) {
    union { float f; unsigned u; } v; v.f = f;
    unsigned r = v.u + 0x7FFF + ((v.u >> 16) & 1);       // RNE
    return (unsigned short)(r >> 16);
}
static __device__ __forceinline__ float bf2f(unsigned short s) {
    union { unsigned u; float f; } v; v.u = ((unsigned)s) << 16;
    return v.f;
}

// DPP cross-lane move within 16-lane rows (VALU pipe)
template <int CTRL>
static __device__ __forceinline__ float dppmv(float x) {
    return __int_as_float(__builtin_amdgcn_mov_dpp(__float_as_int(x), CTRL, 0xF, 0xF, true));
}
static __device__ __forceinline__ float rowsum16(float x) {
    x += dppmv<0xB1>(x);
    x += dppmv<0x4E>(x);
    x += dppmv<0x124>(x);
    x += dppmv<0x128>(x);
    return x;
}

// ---------------- prep: pe->bf16 (+128 zero pad), w_attn^T, w_proj^T ---------
static __device__ __forceinline__ void tcvt_body(const float* __restrict__ src,
                                                 unsigned short* __restrict__ dst,
                                                 int R, int C, int gx, int gy,
                                                 float (*t)[65], int tid) {
    const int c0 = gx * 64, r0 = gy * 64;
    #pragma unroll
    for (int p = 0; p < 4; ++p) {
        const int i = tid + p * 256;
        const int r = i >> 4, c4 = (i & 15) * 4;
        const float4 v = *(const float4*)(src + (long)(r0 + r) * C + c0 + c4);
        t[r][c4] = v.x; t[r][c4+1] = v.y; t[r][c4+2] = v.z; t[r][c4+3] = v.w;
    }
    __syncthreads();
    #pragma unroll
    for (int p = 0; p < 4; ++p) {
        const int i = tid + p * 256;
        const int cr = i >> 4, r4 = (i & 15) * 4;
        ushort4 vv;
        vv.x = f2bf(t[r4+0][cr]); vv.y = f2bf(t[r4+1][cr]);
        vv.z = f2bf(t[r4+2][cr]); vv.w = f2bf(t[r4+3][cr]);
        *(ushort4*)(dst + (long)(c0 + cr) * R + r0 + r4) = vv;
    }
}

__global__ __launch_bounds__(256) void prep(const float* __restrict__ pe,
                                            unsigned short* __restrict__ peb,
                                            const float* __restrict__ wa,
                                            unsigned short* __restrict__ waT,
                                            const float* __restrict__ wp,
                                            unsigned short* __restrict__ wpT) {
    __shared__ float t[64][65];
    const int bx = blockIdx.x, tid = threadIdx.x;
    if (bx < 544) {                              // pe -> [8][2176][32] bf16, pad=0
        const int idx4 = bx * 256 + tid;         // ushort4 granules [8][2176][8]
        const int h   = idx4 / 17408;
        const int rem = idx4 - h * 17408;
        const int u   = rem >> 3;
        const int d4  = (rem & 7) * 4;
        ushort4 o = make_ushort4(0, 0, 0, 0);
        if (u < TT) {
            const float4 v = *(const float4*)(pe + ((long)(h * TT + u)) * HD + d4);
            o.x = f2bf(v.x); o.y = f2bf(v.y); o.z = f2bf(v.z); o.w = f2bf(v.w);
        }
        *(ushort4*)(peb + ((long)(h * TTP + u)) * HD + d4) = o;
    } else if (bx < 592) {
        const int lo = bx - 544;                 // w_attn [256][768] -> [768][256]
        tcvt_body(wa, waT, 256, 768, lo % 12, lo / 12, t, tid);
    } else {
        const int lo = bx - 592;                 // w_proj transpose
        tcvt_body(wp, wpT, 256, 256, lo % 4, lo / 4, t, tid);
    }
}

// ---------------- Kernel A: MFMA qkv GEMM, fp32 A inline-converted -----------
// Q pre-scaled by (1/sqrt(32)) * log2(e); V stored sigma-permuted per 64-block
// (col sigma(t) = 4*(t&15) + ((t>>4)&3)), written via LDS transpose so global
// stores are fully coalesced ushort4 (the R10 scatter cost ~14us in qkv).
__global__ __launch_bounds__(256) void qkv_mfma(const float* __restrict__ xg,
                                                const unsigned short* __restrict__ Bg,
                                                unsigned short* __restrict__ Kb,
                                                unsigned short* __restrict__ Qb,
                                                unsigned short* __restrict__ Vt) {
    __shared__ unsigned short sm[13824];             // 27648 B
    unsigned short* As = sm;                         // [128][72]
    unsigned short* Bs = sm + 9216;                  // [64][72]
    const int tid = threadIdx.x;
    const int wv = tid >> 6, L = tid & 63;
    const int l15 = L & 15, q = L >> 4;
    const int n0 = blockIdx.x * 64;
    const int m0 = blockIdx.y * 128;

    f4 acc[2][4];
    #pragma unroll
    for (int mt = 0; mt < 2; ++mt)
        #pragma unroll
        for (int nt = 0; nt < 4; ++nt) acc[mt][nt] = (f4){0.f,0.f,0.f,0.f};

    for (int kc = 0; kc < 4; ++kc) {
        const int k0 = kc * 64;
        __syncthreads();
        #pragma unroll
        for (int p = 0; p < 4; ++p) {
            const int i = tid + p * 256;
            const int r = i >> 3, c = i & 7;
            const float4 va = *(const float4*)(xg + (long)(m0 + r) * 256 + k0 + c * 8);
            const float4 vb = *(const float4*)(xg + (long)(m0 + r) * 256 + k0 + c * 8 + 4);
            ushort4 lo, hi;
            lo.x = f2bf(va.x); lo.y = f2bf(va.y); lo.z = f2bf(va.z); lo.w = f2bf(va.w);
            hi.x = f2bf(vb.x); hi.y = f2bf(vb.y); hi.z = f2bf(vb.z); hi.w = f2bf(vb.w);
            *(ushort4*)(As + r * 72 + c * 8)     = lo;
            *(ushort4*)(As + r * 72 + c * 8 + 4) = hi;
        }
        #pragma unroll
        for (int p = 0; p < 2; ++p) {
            const int i = tid + p * 256;
            const int r = i >> 3, c = i & 7;
            *(bf8*)(Bs + r * 72 + c * 8) = *(const bf8*)(Bg + (long)(n0 + r) * 256 + k0 + c * 8);
        }
        __syncthreads();
        #pragma unroll
        for (int kk = 0; kk < 2; ++kk) {
            const bf8 a0 = *(const bf8*)(As + (wv * 32 + l15) * 72 + kk * 32 + q * 8);
            const bf8 a1 = *(const bf8*)(As + (wv * 32 + 16 + l15) * 72 + kk * 32 + q * 8);
            #pragma unroll
            for (int nt = 0; nt < 4; ++nt) {
                const bf8 bb = *(const bf8*)(Bs + (nt * 16 + l15) * 72 + kk * 32 + q * 8);
                acc[0][nt] = __builtin_amdgcn_mfma_f32_16x16x32_bf16(a0, bb, acc[0][nt], 0, 0, 0);
                acc[1][nt] = __builtin_amdgcn_mfma_f32_16x16x32_bf16(a1, bb, acc[1][nt], 0, 0, 0);
            }
        }
    }

    const int sec = n0 >> 8;                         // 0=K,1=Q,2=V (block-uniform)
    if (sec == 2) {
        // ---- V epilogue: sigma-permute via LDS transpose, coalesced stores ----
        unsigned short* Vs = sm;                     // [64][132]
        __syncthreads();                             // MFMA-phase LDS reads done
        #pragma unroll
        for (int mt = 0; mt < 2; ++mt) {
            const int sb = (wv >> 1) * 64;           // 64-block within 128-t tile
            const int jb = 16 * q + ((2 * wv + mt) & 3);
            #pragma unroll
            for (int nt = 0; nt < 4; ++nt) {
                const int nl = nt * 16 + l15;        // 0..63
                const f4 a = acc[mt][nt];
                #pragma unroll
                for (int r = 0; r < 4; ++r)
                    Vs[nl * 132 + sb + jb + 4 * r] = f2bf(a[r]);
            }
        }
        __syncthreads();
        const int bloc = m0 >> 11;
        #pragma unroll
        for (int p = 0; p < 8; ++p) {
            const int gid = tid + p * 256;
            const int nl = gid >> 5;                 // 0..63
            const int cg = (gid & 31) * 4;           // t col 0..124
            const int h  = ((n0 - 512) >> 5) + (nl >> 5);
            const long bh = (long)bloc * NH + h;
            *(ushort4*)(Vt + (bh * HD + (nl & 31)) * TT + (m0 & 2047) + cg) =
                *(ushort4*)(Vs + nl * 132 + cg);
        }
        return;
    }
    #pragma unroll
    for (int mt = 0; mt < 2; ++mt) {
        const int gm = m0 + wv * 32 + mt * 16 + q * 4;
        const int b = gm >> 11, tb = gm & 2047;
        #pragma unroll
        for (int nt = 0; nt < 4; ++nt) {
            const int gn = n0 + nt * 16 + l15;
            const int cc = gn & 255, h = cc >> 5, d = cc & 31;
            const long bh = (long)b * NH + h;
            const f4 a = acc[mt][nt];
            if (sec == 1) {
                #pragma unroll
                for (int r = 0; r < 4; ++r)
                    Qb[(bh * TT + tb + r) * HD + d] = f2bf(a[r] * 0.25506655788696527f);
            } else {
                #pragma unroll
                for (int r = 0; r < 4; ++r)
                    Kb[(bh * TT + tb + r) * HD + d] = f2bf(a[r]);
            }
        }
    }
}

// ---------------- Kernel B: flash attention, 128-t tiles, sigma-packed P -----
// 4 waves x 2 sequential 16-row strips; K/V/pe staged once per 64-s tile and
// shared. Static-max softmax (acc init -16); P stored via sigma s-permutation
// so each lane writes one b64 per row (cols 4*l15..+3 = nb). V pre-permuted.
__global__ __launch_bounds__(256) void attn_kernel(const unsigned short* __restrict__ Kb,
                                                   const unsigned short* __restrict__ Qb,
                                                   const unsigned short* __restrict__ Vtg,
                                                   const unsigned short* __restrict__ peb,
                                                   unsigned short* __restrict__ po,
                                                   float* __restrict__ pl) {
    __shared__ unsigned short lds[17152];            // 34304 B
    unsigned short* Ks  = lds;                       // [64][40]
    unsigned short* PEs = lds + 2560;                // [192][40]
    unsigned short* Vts = lds + 10240;               // [32][72]
    unsigned short* Psw = lds + 12544 + (threadIdx.x >> 6) * 1152;  // [16][72]/wave

    const int tid = threadIdx.x;
    const int wv  = tid >> 6;
    const int L   = tid & 63;
    const int l15 = L & 15;
    const int q   = L >> 4;
    const int pair = blockIdx.x >> 1;
    const int sblk = blockIdx.x & 1;
    const int h = blockIdx.y, b = blockIdx.z;
    const long bh = (long)b * NH + h;
    const unsigned short* Kg = Kb  + bh * TT * HD;
    const unsigned short* Qg = Qb  + bh * TT * HD;
    const unsigned short* Vg = Vtg + bh * HD * TT;
    const unsigned short* Pg = peb + (long)h * TTP * HD;

    const int krow = tid >> 2, kc = tid & 3;         // K staging split
    const int vrow = tid >> 3, vc = tid & 7;         // V staging split
    const f4 z4 = {0.f, 0.f, 0.f, 0.f};
    const f4 m4 = {-16.f, -16.f, -16.f, -16.f};      // static softmax max

    int saddr[4]; unsigned psel[4];
    #pragma unroll
    for (int r = 0; r < 4; ++r) {
        const int tcol = l15 + 15 - 4 * q - r;       // 0..30
        saddr[r] = ((q << 4) | (tcol & 15)) << 2;
        psel[r]  = (tcol < 16) ? 0x01000C0Cu : 0x03020C0Cu;
    }

    for (int half = 0; half < 2; ++half) {
        const int itile = half ? 15 - pair : pair;
        const int t0 = itile * 128;

        bf8 aq[2];
        #pragma unroll
        for (int mf = 0; mf < 2; ++mf)
            aq[mf] = *(const bf8*)(Qg + (t0 + wv * 32 + mf * 16 + l15) * HD + q * 8);
        f4 o[2][2];
        o[0][0] = z4; o[0][1] = z4; o[1][0] = z4; o[1][1] = z4;
        float l_st[2][4] = {{0.f,0.f,0.f,0.f},{0.f,0.f,0.f,0.f}};

        const int jtmax = 2 * itile + 1;
        for (int jt = sblk; jt <= jtmax; jt += 2) {
            const int s0 = jt * 64;
            const int ub0 = TT - 128 - t0 + s0;      // pe band base (pad rows = 0)
            __syncthreads();
            *(bf8*)(Ks  + krow * 40 + kc * 8) = *(const bf8*)(Kg + (s0 + krow) * HD + kc * 8);
            *(bf8*)(Vts + vrow * 72 + vc * 8) = *(const bf8*)(Vg + vrow * TT + s0 + vc * 8);
            #pragma unroll
            for (int kk = 0; kk < 3; ++kk) {
                const int i  = tid + kk * 256;
                const int pr = i >> 2, pc = i & 3;
                *(bf8*)(PEs + pr * 40 + pc * 8) = *(const bf8*)(Pg + (long)(ub0 + pr) * HD + pc * 8);
            }
            __syncthreads();

            bf8 bk[4], bva[2], bvb[2];
            #pragma unroll
            for (int nt = 0; nt < 4; ++nt)
                bk[nt] = *(const bf8*)(Ks + (nt * 16 + l15) * 40 + q * 8);
            #pragma unroll
            for (int ks = 0; ks < 2; ++ks) {
                bva[ks] = *(const bf8*)(Vts + l15 * 72 + ks * 32 + q * 8);
                bvb[ks] = *(const bf8*)(Vts + (16 + l15) * 72 + ks * 32 + q * 8);
            }

            #pragma unroll
            for (int mf = 0; mf < 2; ++mf) {
                f4 sa[4], ra[5];
                #pragma unroll
                for (int nt = 0; nt < 4; ++nt)
                    sa[nt] = __builtin_amdgcn_mfma_f32_16x16x32_bf16(aq[mf], bk[nt], m4, 0, 0, 0);
                const int pebs = 112 - wv * 32 - mf * 16;
                #pragma unroll
                for (int nt = 0; nt < 5; ++nt) {
                    const bf8 bp = *(const bf8*)(PEs + (pebs + nt * 16 + l15) * 40 + q * 8);
                    ra[nt] = __builtin_amdgcn_mfma_f32_16x16x32_bf16(aq[mf], bp, z4, 0, 0, 0);
                }

                // skew gather: v_perm pack + bpermute + v_perm select
                #pragma unroll
                for (int nb = 0; nb < 4; ++nb) {
                    #pragma unroll
                    for (int r = 0; r < 4; ++r) {
                        const unsigned packed = __builtin_amdgcn_perm(
                            (unsigned)__float_as_int(ra[nb + 1][r]),
                            (unsigned)__float_as_int(ra[nb][r]), 0x07060302u);
                        const int v = __builtin_amdgcn_ds_bpermute(saddr[r], (int)packed);
                        const unsigned sel = __builtin_amdgcn_perm((unsigned)v, (unsigned)v, psel[r]);
                        sa[nb][r] += __int_as_float((int)sel);
                    }
                }

                if (s0 + 63 > t0 + wv * 32 + mf * 16) {      // causal mask
                    #pragma unroll
                    for (int nb = 0; nb < 4; ++nb)
                        #pragma unroll
                        for (int r = 0; r < 4; ++r) {
                            const int s_l = s0 + nb * 16 + l15;
                            const int t_l = t0 + wv * 32 + mf * 16 + 4 * q + r;
                            if (s_l > t_l) sa[nb][r] = -1e30f;
                        }
                }

                // static-max softmax; P packed b64 at sigma-cols 4*l15..+3
                #pragma unroll
                for (int r = 0; r < 4; ++r) {
                    const float p0 = exp2f(sa[0][r]);
                    const float p1 = exp2f(sa[1][r]);
                    const float p2 = exp2f(sa[2][r]);
                    const float p3 = exp2f(sa[3][r]);
                    l_st[mf][r] += (p0 + p1) + (p2 + p3);
                    const unsigned a0 = (unsigned)__float_as_int(p0) + 0x8000u;
                    const unsigned a1 = (unsigned)__float_as_int(p1) + 0x8000u;
                    const unsigned a2 = (unsigned)__float_as_int(p2) + 0x8000u;
                    const unsigned a3 = (unsigned)__float_as_int(p3) + 0x8000u;
                    uint2 w;
                    w.x = __builtin_amdgcn_perm(a1, a0, 0x07060302u);
                    w.y = __builtin_amdgcn_perm(a3, a2, 0x07060302u);
                    *(uint2*)(Psw + (4 * q + r) * 72 + 4 * l15) = w;
                }

                // PV (k-axis in shared sigma order)
                #pragma unroll
                for (int ks = 0; ks < 2; ++ks) {
                    const bf8 ap = *(const bf8*)(Psw + l15 * 72 + ks * 32 + q * 8);
                    o[mf][0] = __builtin_amdgcn_mfma_f32_16x16x32_bf16(ap, bva[ks], o[mf][0], 0, 0, 0);
                    o[mf][1] = __builtin_amdgcn_mfma_f32_16x16x32_bf16(ap, bvb[ks], o[mf][1], 0, 0, 0);
                }
            }
        }

        // epilogue: raw partial O (bf16) + row l
        const long pt = (bh * 16 + itile) * 2 + sblk;
        unsigned short* pob = po + pt * 4096;
        #pragma unroll
        for (int mf = 0; mf < 2; ++mf)
            #pragma unroll
            for (int r = 0; r < 4; ++r) {
                const int row = wv * 32 + mf * 16 + 4 * q + r;
                pob[row * 32 + l15]      = f2bf(o[mf][0][r]);
                pob[row * 32 + 16 + l15] = f2bf(o[mf][1][r]);
                const float ls = rowsum16(l_st[mf][r]);
                if (l15 == 0) pl[pt * 128 + row] = ls;
            }
    }
}

// ---------------- Kernel C: proj GEMM + fused s-split merge + bias -----------
__global__ __launch_bounds__(256) void proj_mfma(const unsigned short* __restrict__ po,
                                                 const float* __restrict__ pl,
                                                 const unsigned short* __restrict__ Bg,
                                                 const float* __restrict__ bias,
                                                 float* __restrict__ out) {
    __shared__ unsigned short sm[13824];
    unsigned short* As = sm;                         // [128][72]
    unsigned short* Bs = sm + 9216;                  // [64][72]
    const int tid = threadIdx.x;
    const int wv = tid >> 6, L = tid & 63;
    const int l15 = L & 15, q = L >> 4;
    const int n0 = blockIdx.x * 64;
    const int m0 = blockIdx.y * 128;

    f4 acc[2][4];
    #pragma unroll
    for (int mt = 0; mt < 2; ++mt)
        #pragma unroll
        for (int nt = 0; nt < 4; ++nt) acc[mt][nt] = (f4){0.f,0.f,0.f,0.f};

    for (int kc = 0; kc < 4; ++kc) {
        const int k0 = kc * 64;
        __syncthreads();
        #pragma unroll
        for (int p = 0; p < 4; ++p) {
            const int i = tid + p * 256;
            const int r = i >> 3, c = i & 7;
            const int gm = m0 + r;
            const int bloc = gm >> 11, t = gm & 2047;
            const int k = k0 + c * 8;
            const int hh = k >> 5, d0 = k & 31;
            const int tile = t >> 7, row = t & 127;
            const long pt0 = ((long)(bloc * NH + hh) * 16 + tile) * 2;
            const float l0 = pl[pt0 * 128 + row];
            const float l1 = pl[pt0 * 128 + 128 + row];
            const float inv = 1.0f / (l0 + l1);
            const unsigned short* p0 = po + pt0 * 4096 + row * 32 + d0;
            const unsigned short* p1 = p0 + 4096;
            const ushort4 a0 = *(const ushort4*)p0;
            const ushort4 a1 = *(const ushort4*)(p0 + 4);
            const ushort4 c0 = *(const ushort4*)p1;
            const ushort4 c1 = *(const ushort4*)(p1 + 4);
            ushort4 o0, o1;
            o0.x = f2bf((bf2f(a0.x) + bf2f(c0.x)) * inv);
            o0.y = f2bf((bf2f(a0.y) + bf2f(c0.y)) * inv);
            o0.z = f2bf((bf2f(a0.z) + bf2f(c0.z)) * inv);
            o0.w = f2bf((bf2f(a0.w) + bf2f(c0.w)) * inv);
            o1.x = f2bf((bf2f(a1.x) + bf2f(c1.x)) * inv);
            o1.y = f2bf((bf2f(a1.y) + bf2f(c1.y)) * inv);
            o1.z = f2bf((bf2f(a1.z) + bf2f(c1.z)) * inv);
            o1.w = f2bf((bf2f(a1.w) + bf2f(c1.w)) * inv);
            *(ushort4*)(As + r * 72 + c * 8)     = o0;
            *(ushort4*)(As + r * 72 + c * 8 + 4) = o1;
        }
        #pragma unroll
        for (int p = 0; p < 2; ++p) {
            const int i = tid + p * 256;
            const int r = i >> 3, c = i & 7;
            *(bf8*)(Bs + r * 72 + c * 8) = *(const bf8*)(Bg + (long)(n0 + r) * 256 + k0 + c * 8);
        }
        __syncthreads();
        #pragma unroll
        for (int kk = 0; kk < 2; ++kk) {
            const bf8 a0 = *(const bf8*)(As + (wv * 32 + l15) * 72 + kk * 32 + q * 8);
            const bf8 a1 = *(const bf8*)(As + (wv * 32 + 16 + l15) * 72 + kk * 32 + q * 8);
            #pragma unroll
            for (int nt = 0; nt < 4; ++nt) {
                const bf8 bb = *(const bf8*)(Bs + (nt * 16 + l15) * 72 + kk * 32 + q * 8);
                acc[0][nt] = __builtin_amdgcn_mfma_f32_16x16x32_bf16(a0, bb, acc[0][nt], 0, 0, 0);
                acc[1][nt] = __builtin_amdgcn_mfma_f32_16x16x32_bf16(a1, bb, acc[1][nt], 0, 0, 0);
            }
        }
    }

    #pragma unroll
    for (int mt = 0; mt < 2; ++mt) {
        const int gm = m0 + wv * 32 + mt * 16 + q * 4;
        #pragma unroll
        for (int nt = 0; nt < 4; ++nt) {
            const int gn = n0 + nt * 16 + l15;
            const float bv = bias[gn];
            #pragma unroll
            for (int r = 0; r < 4; ++r)
                out[(long)(gm + r) * NEMB + gn] = acc[mt][nt][r] + bv;
        }
    }
}

extern "C" void kernel_launch(void* const* d_in, const int* in_sizes, int n_in,
                              void* d_out, int out_size, void* d_ws, size_t ws_size,
                              hipStream_t stream) {
    const float* x      = (const float*)d_in[0];
    const float* w_attn = (const float*)d_in[1];
    const float* pe     = (const float*)d_in[2];
    const float* w_proj = (const float*)d_in[3];
    const float* b_proj = (const float*)d_in[4];
    float* out = (float*)d_out;

    char* base = (char*)d_ws;
    unsigned short* Kb   = (unsigned short*)(base);                        // 4 MB
    unsigned short* Qb   = (unsigned short*)(base + ( 4u << 20));          // 4 MB
    unsigned short* Vt   = (unsigned short*)(base + ( 8u << 20));          // 4 MB
    unsigned short* peb  = (unsigned short*)(base + (12u << 20));          // 1.06 MB
    unsigned short* waT  = (unsigned short*)(base + (14u << 20));          // 384 KB
    unsigned short* wpT  = (unsigned short*)(base + (29u << 19));          // 128 KB @14.5MB
    unsigned short* po   = (unsigned short*)(base + (15u << 20));          // 8 MB
    float*          pl   = (float*)        (base + (23u << 20));           // 512 KB

    prep<<<dim3(608), 256, 0, stream>>>(pe, peb, w_attn, waT, w_proj, wpT);
    qkv_mfma<<<dim3(12, 64), 256, 0, stream>>>(x, waT, Kb, Qb, Vt);
    attn_kernel<<<dim3(16, NH, BB), 256, 0, stream>>>(Kb, Qb, Vt, peb, po, pl);
    proj_mfma<<<dim3(4, 64), 256, 0, stream>>>(po, pl, wpT, b_proj, out);
}

// Round 12
// 157.198 us; speedup vs baseline: 1.1951x; 1.0057x over previous
//
#include <hip/hip_runtime.h>
#include <math.h>

#define BB 4
#define TT 2048
#define TTP 2176   // TT + 128 zero pad rows per head (pe)
#define NEMB 256
#define NH 8
#define HD 32

typedef __attribute__((ext_vector_type(8))) short bf8;   // 8 x bf16 (4 VGPRs)
typedef __attribute__((ext_vector_type(4))) float f4;    // MFMA C/D

static __device__ __forceinline__ unsigned short f2bf(float f) {
    union { float f; unsigned u; } v; v.f = f;
    unsigned r = v.u + 0x7FFF + ((v.u >> 16) & 1);       // RNE
    return (unsigned short)(r >> 16);
}
static __device__ __forceinline__ float bf2f(unsigned short s) {
    union { unsigned u; float f; } v; v.u = ((unsigned)s) << 16;
    return v.f;
}

// DPP cross-lane move within 16-lane rows (VALU pipe)
template <int CTRL>
static __device__ __forceinline__ float dppmv(float x) {
    return __int_as_float(__builtin_amdgcn_mov_dpp(__float_as_int(x), CTRL, 0xF, 0xF, true));
}
static __device__ __forceinline__ float rowsum16(float x) {
    x += dppmv<0xB1>(x);
    x += dppmv<0x4E>(x);
    x += dppmv<0x124>(x);
    x += dppmv<0x128>(x);
    return x;
}

// ---------------- prep: pe->bf16 (+128 zero pad), w_attn^T, w_proj^T ---------
static __device__ __forceinline__ void tcvt_body(const float* __restrict__ src,
                                                 unsigned short* __restrict__ dst,
                                                 int R, int C, int gx, int gy,
                                                 float (*t)[65], int tid) {
    const int c0 = gx * 64, r0 = gy * 64;
    #pragma unroll
    for (int p = 0; p < 4; ++p) {
        const int i = tid + p * 256;
        const int r = i >> 4, c4 = (i & 15) * 4;
        const float4 v = *(const float4*)(src + (long)(r0 + r) * C + c0 + c4);
        t[r][c4] = v.x; t[r][c4+1] = v.y; t[r][c4+2] = v.z; t[r][c4+3] = v.w;
    }
    __syncthreads();
    #pragma unroll
    for (int p = 0; p < 4; ++p) {
        const int i = tid + p * 256;
        const int cr = i >> 4, r4 = (i & 15) * 4;
        ushort4 vv;
        vv.x = f2bf(t[r4+0][cr]); vv.y = f2bf(t[r4+1][cr]);
        vv.z = f2bf(t[r4+2][cr]); vv.w = f2bf(t[r4+3][cr]);
        *(ushort4*)(dst + (long)(c0 + cr) * R + r0 + r4) = vv;
    }
}

__global__ __launch_bounds__(256) void prep(const float* __restrict__ pe,
                                            unsigned short* __restrict__ peb,
                                            const float* __restrict__ wa,
                                            unsigned short* __restrict__ waT,
                                            const float* __restrict__ wp,
                                            unsigned short* __restrict__ wpT) {
    __shared__ float t[64][65];
    const int bx = blockIdx.x, tid = threadIdx.x;
    if (bx < 544) {                              // pe -> [8][2176][32] bf16, pad=0
        const int idx4 = bx * 256 + tid;         // ushort4 granules [8][2176][8]
        const int h   = idx4 / 17408;
        const int rem = idx4 - h * 17408;
        const int u   = rem >> 3;
        const int d4  = (rem & 7) * 4;
        ushort4 o = make_ushort4(0, 0, 0, 0);
        if (u < TT) {
            const float4 v = *(const float4*)(pe + ((long)(h * TT + u)) * HD + d4);
            o.x = f2bf(v.x); o.y = f2bf(v.y); o.z = f2bf(v.z); o.w = f2bf(v.w);
        }
        *(ushort4*)(peb + ((long)(h * TTP + u)) * HD + d4) = o;
    } else if (bx < 592) {
        const int lo = bx - 544;                 // w_attn [256][768] -> [768][256]
        tcvt_body(wa, waT, 256, 768, lo % 12, lo / 12, t, tid);
    } else {
        const int lo = bx - 592;                 // w_proj transpose
        tcvt_body(wp, wpT, 256, 256, lo % 4, lo / 4, t, tid);
    }
}

// ---------------- Kernel A: MFMA qkv GEMM, fp32 A inline-converted -----------
// Q pre-scaled by (1/sqrt(32)) * log2(e); V stored sigma-permuted per 64-block
// (col sigma(t) = 4*(t&15) + ((t>>4)&3)). ALL epilogues go through an LDS
// transpose so global stores are coalesced ushort4 (scattered 2B stores cost
// ~14us in R10's qkv).
__global__ __launch_bounds__(256) void qkv_mfma(const float* __restrict__ xg,
                                                const unsigned short* __restrict__ Bg,
                                                unsigned short* __restrict__ Kb,
                                                unsigned short* __restrict__ Qb,
                                                unsigned short* __restrict__ Vt) {
    __shared__ unsigned short sm[13824];             // 27648 B
    unsigned short* As = sm;                         // [128][72]
    unsigned short* Bs = sm + 9216;                  // [64][72]
    const int tid = threadIdx.x;
    const int wv = tid >> 6, L = tid & 63;
    const int l15 = L & 15, q = L >> 4;
    const int n0 = blockIdx.x * 64;
    const int m0 = blockIdx.y * 128;

    f4 acc[2][4];
    #pragma unroll
    for (int mt = 0; mt < 2; ++mt)
        #pragma unroll
        for (int nt = 0; nt < 4; ++nt) acc[mt][nt] = (f4){0.f,0.f,0.f,0.f};

    for (int kc = 0; kc < 4; ++kc) {
        const int k0 = kc * 64;
        __syncthreads();
        #pragma unroll
        for (int p = 0; p < 4; ++p) {
            const int i = tid + p * 256;
            const int r = i >> 3, c = i & 7;
            const float4 va = *(const float4*)(xg + (long)(m0 + r) * 256 + k0 + c * 8);
            const float4 vb = *(const float4*)(xg + (long)(m0 + r) * 256 + k0 + c * 8 + 4);
            ushort4 lo, hi;
            lo.x = f2bf(va.x); lo.y = f2bf(va.y); lo.z = f2bf(va.z); lo.w = f2bf(va.w);
            hi.x = f2bf(vb.x); hi.y = f2bf(vb.y); hi.z = f2bf(vb.z); hi.w = f2bf(vb.w);
            *(ushort4*)(As + r * 72 + c * 8)     = lo;
            *(ushort4*)(As + r * 72 + c * 8 + 4) = hi;
        }
        #pragma unroll
        for (int p = 0; p < 2; ++p) {
            const int i = tid + p * 256;
            const int r = i >> 3, c = i & 7;
            *(bf8*)(Bs + r * 72 + c * 8) = *(const bf8*)(Bg + (long)(n0 + r) * 256 + k0 + c * 8);
        }
        __syncthreads();
        #pragma unroll
        for (int kk = 0; kk < 2; ++kk) {
            const bf8 a0 = *(const bf8*)(As + (wv * 32 + l15) * 72 + kk * 32 + q * 8);
            const bf8 a1 = *(const bf8*)(As + (wv * 32 + 16 + l15) * 72 + kk * 32 + q * 8);
            #pragma unroll
            for (int nt = 0; nt < 4; ++nt) {
                const bf8 bb = *(const bf8*)(Bs + (nt * 16 + l15) * 72 + kk * 32 + q * 8);
                acc[0][nt] = __builtin_amdgcn_mfma_f32_16x16x32_bf16(a0, bb, acc[0][nt], 0, 0, 0);
                acc[1][nt] = __builtin_amdgcn_mfma_f32_16x16x32_bf16(a1, bb, acc[1][nt], 0, 0, 0);
            }
        }
    }

    const int sec = n0 >> 8;                         // 0=K,1=Q,2=V (block-uniform)
    if (sec == 2) {
        // ---- V epilogue: sigma-permute via LDS transpose, coalesced stores ----
        unsigned short* Vs = sm;                     // [64][132]
        __syncthreads();                             // MFMA-phase LDS reads done
        #pragma unroll
        for (int mt = 0; mt < 2; ++mt) {
            const int sb = (wv >> 1) * 64;           // 64-block within 128-t tile
            const int jb = 16 * q + ((2 * wv + mt) & 3);
            #pragma unroll
            for (int nt = 0; nt < 4; ++nt) {
                const int nl = nt * 16 + l15;        // 0..63
                const f4 a = acc[mt][nt];
                #pragma unroll
                for (int r = 0; r < 4; ++r)
                    Vs[nl * 132 + sb + jb + 4 * r] = f2bf(a[r]);
            }
        }
        __syncthreads();
        const int bloc = m0 >> 11;
        #pragma unroll
        for (int p = 0; p < 8; ++p) {
            const int gid = tid + p * 256;
            const int nl = gid >> 5;                 // 0..63
            const int cg = (gid & 31) * 4;           // t col 0..124
            const int h  = ((n0 - 512) >> 5) + (nl >> 5);
            const long bh = (long)bloc * NH + h;
            *(ushort4*)(Vt + (bh * HD + (nl & 31)) * TT + (m0 & 2047) + cg) =
                *(ushort4*)(Vs + nl * 132 + cg);
        }
        return;
    }
    // ---- K/Q epilogue: LDS transpose -> coalesced ushort4 stores ----
    {
        unsigned short* Ts = sm;                     // [128][68]
        const float qsc = (sec == 1) ? 0.25506655788696527f : 1.0f;
        __syncthreads();                             // MFMA-phase LDS reads done
        #pragma unroll
        for (int mt = 0; mt < 2; ++mt) {
            const int tl0 = wv * 32 + mt * 16 + q * 4;
            #pragma unroll
            for (int nt = 0; nt < 4; ++nt) {
                const int nl = nt * 16 + l15;
                const f4 a = acc[mt][nt];
                #pragma unroll
                for (int r = 0; r < 4; ++r)
                    Ts[(tl0 + r) * 68 + nl] = f2bf(a[r] * qsc);
            }
        }
        __syncthreads();
        const int bloc = m0 >> 11;
        unsigned short* dst = (sec == 1) ? Qb : Kb;
        #pragma unroll
        for (int p = 0; p < 8; ++p) {
            const int gid = tid + p * 256;
            const int tl = gid >> 4;                 // 0..127
            const int c4 = (gid & 15) * 4;           // 0..60
            const int h  = ((n0 & 255) >> 5) + (c4 >> 5);
            const int d  = c4 & 31;
            const long bh = (long)bloc * NH + h;
            const int t = (m0 & 2047) + tl;
            *(ushort4*)(dst + (bh * TT + t) * HD + d) = *(ushort4*)(Ts + tl * 68 + c4);
        }
    }
}

// ---------------- Kernel B: flash attention, 128-t tiles, sigma-packed P -----
// 4 waves x 2 sequential 16-row strips; K/V/pe staged once per 64-s tile and
// shared. Static-max softmax (acc init -16); P stored via sigma s-permutation
// so each lane writes one b64 per row. V pre-permuted. pe frags: the two
// strips' bands overlap 64 rows -> read 6 unique b128 frags, not 10.
__global__ __launch_bounds__(256) void attn_kernel(const unsigned short* __restrict__ Kb,
                                                   const unsigned short* __restrict__ Qb,
                                                   const unsigned short* __restrict__ Vtg,
                                                   const unsigned short* __restrict__ peb,
                                                   unsigned short* __restrict__ po,
                                                   float* __restrict__ pl) {
    __shared__ unsigned short lds[17152];            // 34304 B
    unsigned short* Ks  = lds;                       // [64][40]
    unsigned short* PEs = lds + 2560;                // [192][40]
    unsigned short* Vts = lds + 10240;               // [32][72]
    unsigned short* Psw = lds + 12544 + (threadIdx.x >> 6) * 1152;  // [16][72]/wave

    const int tid = threadIdx.x;
    const int wv  = tid >> 6;
    const int L   = tid & 63;
    const int l15 = L & 15;
    const int q   = L >> 4;
    const int pair = blockIdx.x >> 1;
    const int sblk = blockIdx.x & 1;
    const int h = blockIdx.y, b = blockIdx.z;
    const long bh = (long)b * NH + h;
    const unsigned short* Kg = Kb  + bh * TT * HD;
    const unsigned short* Qg = Qb  + bh * TT * HD;
    const unsigned short* Vg = Vtg + bh * HD * TT;
    const unsigned short* Pg = peb + (long)h * TTP * HD;

    const int krow = tid >> 2, kc = tid & 3;         // K staging split
    const int vrow = tid >> 3, vc = tid & 7;         // V staging split
    const f4 z4 = {0.f, 0.f, 0.f, 0.f};
    const f4 m4 = {-16.f, -16.f, -16.f, -16.f};      // static softmax max

    int saddr[4]; unsigned psel[4];
    #pragma unroll
    for (int r = 0; r < 4; ++r) {
        const int tcol = l15 + 15 - 4 * q - r;       // 0..30
        saddr[r] = ((q << 4) | (tcol & 15)) << 2;
        psel[r]  = (tcol < 16) ? 0x01000C0Cu : 0x03020C0Cu;
    }

    for (int half = 0; half < 2; ++half) {
        const int itile = half ? 15 - pair : pair;
        const int t0 = itile * 128;

        bf8 aq[2];
        #pragma unroll
        for (int mf = 0; mf < 2; ++mf)
            aq[mf] = *(const bf8*)(Qg + (t0 + wv * 32 + mf * 16 + l15) * HD + q * 8);
        f4 o[2][2];
        o[0][0] = z4; o[0][1] = z4; o[1][0] = z4; o[1][1] = z4;
        float l_st[2][4] = {{0.f,0.f,0.f,0.f},{0.f,0.f,0.f,0.f}};

        const int jtmax = 2 * itile + 1;
        for (int jt = sblk; jt <= jtmax; jt += 2) {
            const int s0 = jt * 64;
            const int ub0 = TT - 128 - t0 + s0;      // pe band base (pad rows = 0)
            __syncthreads();
            *(bf8*)(Ks  + krow * 40 + kc * 8) = *(const bf8*)(Kg + (s0 + krow) * HD + kc * 8);
            *(bf8*)(Vts + vrow * 72 + vc * 8) = *(const bf8*)(Vg + vrow * TT + s0 + vc * 8);
            #pragma unroll
            for (int kk = 0; kk < 3; ++kk) {
                const int i  = tid + kk * 256;
                const int pr = i >> 2, pc = i & 3;
                *(bf8*)(PEs + pr * 40 + pc * 8) = *(const bf8*)(Pg + (long)(ub0 + pr) * HD + pc * 8);
            }
            __syncthreads();

            bf8 bk[4], bva[2], bvb[2], bp[6];
            #pragma unroll
            for (int nt = 0; nt < 4; ++nt)
                bk[nt] = *(const bf8*)(Ks + (nt * 16 + l15) * 40 + q * 8);
            #pragma unroll
            for (int ks = 0; ks < 2; ++ks) {
                bva[ks] = *(const bf8*)(Vts + l15 * 72 + ks * 32 + q * 8);
                bvb[ks] = *(const bf8*)(Vts + (16 + l15) * 72 + ks * 32 + q * 8);
            }
            const int pebs1 = 96 - wv * 32;          // strip mf=1 band base
            #pragma unroll
            for (int j = 0; j < 6; ++j)
                bp[j] = *(const bf8*)(PEs + (pebs1 + j * 16 + l15) * 40 + q * 8);

            #pragma unroll
            for (int mf = 0; mf < 2; ++mf) {
                f4 sa[4], ra[5];
                #pragma unroll
                for (int nt = 0; nt < 4; ++nt)
                    sa[nt] = __builtin_amdgcn_mfma_f32_16x16x32_bf16(aq[mf], bk[nt], m4, 0, 0, 0);
                #pragma unroll
                for (int nt = 0; nt < 5; ++nt)
                    ra[nt] = __builtin_amdgcn_mfma_f32_16x16x32_bf16(aq[mf], bp[nt + 1 - mf], z4, 0, 0, 0);

                // skew gather: v_perm pack + bpermute + v_perm select
                #pragma unroll
                for (int nb = 0; nb < 4; ++nb) {
                    #pragma unroll
                    for (int r = 0; r < 4; ++r) {
                        const unsigned packed = __builtin_amdgcn_perm(
                            (unsigned)__float_as_int(ra[nb + 1][r]),
                            (unsigned)__float_as_int(ra[nb][r]), 0x07060302u);
                        const int v = __builtin_amdgcn_ds_bpermute(saddr[r], (int)packed);
                        const unsigned sel = __builtin_amdgcn_perm((unsigned)v, (unsigned)v, psel[r]);
                        sa[nb][r] += __int_as_float((int)sel);
                    }
                }

                if (s0 + 63 > t0 + wv * 32 + mf * 16) {      // causal mask
                    #pragma unroll
                    for (int nb = 0; nb < 4; ++nb)
                        #pragma unroll
                        for (int r = 0; r < 4; ++r) {
                            const int s_l = s0 + nb * 16 + l15;
                            const int t_l = t0 + wv * 32 + mf * 16 + 4 * q + r;
                            if (s_l > t_l) sa[nb][r] = -1e30f;
                        }
                }

                // static-max softmax; P packed b64 at sigma-cols 4*l15..+3
                #pragma unroll
                for (int r = 0; r < 4; ++r) {
                    const float p0 = exp2f(sa[0][r]);
                    const float p1 = exp2f(sa[1][r]);
                    const float p2 = exp2f(sa[2][r]);
                    const float p3 = exp2f(sa[3][r]);
                    l_st[mf][r] += (p0 + p1) + (p2 + p3);
                    const unsigned a0 = (unsigned)__float_as_int(p0) + 0x8000u;
                    const unsigned a1 = (unsigned)__float_as_int(p1) + 0x8000u;
                    const unsigned a2 = (unsigned)__float_as_int(p2) + 0x8000u;
                    const unsigned a3 = (unsigned)__float_as_int(p3) + 0x8000u;
                    uint2 w;
                    w.x = __builtin_amdgcn_perm(a1, a0, 0x07060302u);
                    w.y = __builtin_amdgcn_perm(a3, a2, 0x07060302u);
                    *(uint2*)(Psw + (4 * q + r) * 72 + 4 * l15) = w;
                }

                // PV (k-axis in shared sigma order)
                #pragma unroll
                for (int ks = 0; ks < 2; ++ks) {
                    const bf8 ap = *(const bf8*)(Psw + l15 * 72 + ks * 32 + q * 8);
                    o[mf][0] = __builtin_amdgcn_mfma_f32_16x16x32_bf16(ap, bva[ks], o[mf][0], 0, 0, 0);
                    o[mf][1] = __builtin_amdgcn_mfma_f32_16x16x32_bf16(ap, bvb[ks], o[mf][1], 0, 0, 0);
                }
            }
        }

        // epilogue: raw partial O (bf16) + row l
        const long pt = (bh * 16 + itile) * 2 + sblk;
        unsigned short* pob = po + pt * 4096;
        #pragma unroll
        for (int mf = 0; mf < 2; ++mf)
            #pragma unroll
            for (int r = 0; r < 4; ++r) {
                const int row = wv * 32 + mf * 16 + 4 * q + r;
                pob[row * 32 + l15]      = f2bf(o[mf][0][r]);
                pob[row * 32 + 16 + l15] = f2bf(o[mf][1][r]);
                const float ls = rowsum16(l_st[mf][r]);
                if (l15 == 0) pl[pt * 128 + row] = ls;
            }
    }
}

// ---------------- Kernel C: proj GEMM + fused s-split merge + bias -----------
__global__ __launch_bounds__(256) void proj_mfma(const unsigned short* __restrict__ po,
                                                 const float* __restrict__ pl,
                                                 const unsigned short* __restrict__ Bg,
                                                 const float* __restrict__ bias,
                                                 float* __restrict__ out) {
    __shared__ unsigned short sm[13824];
    unsigned short* As = sm;                         // [128][72]
    unsigned short* Bs = sm + 9216;                  // [64][72]
    const int tid = threadIdx.x;
    const int wv = tid >> 6, L = tid & 63;
    const int l15 = L & 15, q = L >> 4;
    const int n0 = blockIdx.x * 64;
    const int m0 = blockIdx.y * 128;

    f4 acc[2][4];
    #pragma unroll
    for (int mt = 0; mt < 2; ++mt)
        #pragma unroll
        for (int nt = 0; nt < 4; ++nt) acc[mt][nt] = (f4){0.f,0.f,0.f,0.f};

    for (int kc = 0; kc < 4; ++kc) {
        const int k0 = kc * 64;
        __syncthreads();
        #pragma unroll
        for (int p = 0; p < 4; ++p) {
            const int i = tid + p * 256;
            const int r = i >> 3, c = i & 7;
            const int gm = m0 + r;
            const int bloc = gm >> 11, t = gm & 2047;
            const int k = k0 + c * 8;
            const int hh = k >> 5, d0 = k & 31;
            const int tile = t >> 7, row = t & 127;
            const long pt0 = ((long)(bloc * NH + hh) * 16 + tile) * 2;
            const float l0 = pl[pt0 * 128 + row];
            const float l1 = pl[pt0 * 128 + 128 + row];
            const float inv = 1.0f / (l0 + l1);
            const unsigned short* p0 = po + pt0 * 4096 + row * 32 + d0;
            const unsigned short* p1 = p0 + 4096;
            const ushort4 a0 = *(const ushort4*)p0;
            const ushort4 a1 = *(const ushort4*)(p0 + 4);
            const ushort4 c0 = *(const ushort4*)p1;
            const ushort4 c1 = *(const ushort4*)(p1 + 4);
            ushort4 o0, o1;
            o0.x = f2bf((bf2f(a0.x) + bf2f(c0.x)) * inv);
            o0.y = f2bf((bf2f(a0.y) + bf2f(c0.y)) * inv);
            o0.z = f2bf((bf2f(a0.z) + bf2f(c0.z)) * inv);
            o0.w = f2bf((bf2f(a0.w) + bf2f(c0.w)) * inv);
            o1.x = f2bf((bf2f(a1.x) + bf2f(c1.x)) * inv);
            o1.y = f2bf((bf2f(a1.y) + bf2f(c1.y)) * inv);
            o1.z = f2bf((bf2f(a1.z) + bf2f(c1.z)) * inv);
            o1.w = f2bf((bf2f(a1.w) + bf2f(c1.w)) * inv);
            *(ushort4*)(As + r * 72 + c * 8)     = o0;
            *(ushort4*)(As + r * 72 + c * 8 + 4) = o1;
        }
        #pragma unroll
        for (int p = 0; p < 2; ++p) {
            const int i = tid + p * 256;
            const int r = i >> 3, c = i & 7;
            *(bf8*)(Bs + r * 72 + c * 8) = *(const bf8*)(Bg + (long)(n0 + r) * 256 + k0 + c * 8);
        }
        __syncthreads();
        #pragma unroll
        for (int kk = 0; kk < 2; ++kk) {
            const bf8 a0 = *(const bf8*)(As + (wv * 32 + l15) * 72 + kk * 32 + q * 8);
            const bf8 a1 = *(const bf8*)(As + (wv * 32 + 16 + l15) * 72 + kk * 32 + q * 8);
            #pragma unroll
            for (int nt = 0; nt < 4; ++nt) {
                const bf8 bb = *(const bf8*)(Bs + (nt * 16 + l15) * 72 + kk * 32 + q * 8);
                acc[0][nt] = __builtin_amdgcn_mfma_f32_16x16x32_bf16(a0, bb, acc[0][nt], 0, 0, 0);
                acc[1][nt] = __builtin_amdgcn_mfma_f32_16x16x32_bf16(a1, bb, acc[1][nt], 0, 0, 0);
            }
        }
    }

    #pragma unroll
    for (int mt = 0; mt < 2; ++mt) {
        const int gm = m0 + wv * 32 + mt * 16 + q * 4;
        #pragma unroll
        for (int nt = 0; nt < 4; ++nt) {
            const int gn = n0 + nt * 16 + l15;
            const float bv = bias[gn];
            #pragma unroll
            for (int r = 0; r < 4; ++r)
                out[(long)(gm + r) * NEMB + gn] = acc[mt][nt][r] + bv;
        }
    }
}

extern "C" void kernel_launch(void* const* d_in, const int* in_sizes, int n_in,
                              void* d_out, int out_size, void* d_ws, size_t ws_size,
                              hipStream_t stream) {
    const float* x      = (const float*)d_in[0];
    const float* w_attn = (const float*)d_in[1];
    const float* pe     = (const float*)d_in[2];
    const float* w_proj = (const float*)d_in[3];
    const float* b_proj = (const float*)d_in[4];
    float* out = (float*)d_out;

    char* base = (char*)d_ws;
    unsigned short* Kb   = (unsigned short*)(base);                        // 4 MB
    unsigned short* Qb   = (unsigned short*)(base + ( 4u << 20));          // 4 MB
    unsigned short* Vt   = (unsigned short*)(base + ( 8u << 20));          // 4 MB
    unsigned short* peb  = (unsigned short*)(base + (12u << 20));          // 1.06 MB
    unsigned short* waT  = (unsigned short*)(base + (14u << 20));          // 384 KB
    unsigned short* wpT  = (unsigned short*)(base + (29u << 19));          // 128 KB @14.5MB
    unsigned short* po   = (unsigned short*)(base + (15u << 20));          // 8 MB
    float*          pl   = (float*)        (base + (23u << 20));           // 512 KB

    prep<<<dim3(608), 256, 0, stream>>>(pe, peb, w_attn, waT, w_proj, wpT);
    qkv_mfma<<<dim3(12, 64), 256, 0, stream>>>(x, waT, Kb, Qb, Vt);
    attn_kernel<<<dim3(16, NH, BB), 256, 0, stream>>>(Kb, Qb, Vt, peb, po, pl);
    proj_mfma<<<dim3(4, 64), 256, 0, stream>>>(po, pl, wpT, b_proj, out);
}